// Round 6
// baseline (358.072 us; speedup 1.0000x reference)
//
#include <hip/hip_runtime.h>

#define N_NODES 50000
#define BN_EPS 1e-5f
#define SCAN_CHUNK 2048

typedef __attribute__((ext_vector_type(8))) short short8;
typedef __attribute__((ext_vector_type(4))) float f32x4;

__device__ __forceinline__ unsigned short f2b(float x) {
    unsigned int u = __float_as_uint(x);
    unsigned int r = (u + 0x7fffu + ((u >> 16) & 1u)) >> 16;
    return (unsigned short)r;
}
__device__ __forceinline__ float b2f_lo(unsigned int u) { return __uint_as_float(u << 16); }
__device__ __forceinline__ float b2f_hi(unsigned int u) { return __uint_as_float(u & 0xffff0000u); }
__device__ __forceinline__ unsigned int pack2(float lo, float hi) {
    return (unsigned int)f2b(lo) | ((unsigned int)f2b(hi) << 16);
}
__device__ __forceinline__ float us2f(unsigned short s) {
    return __uint_as_float(((unsigned int)s) << 16);
}

// ---------------- edge dtype detector ----------------
__global__ void k_detect64(const int* __restrict__ e, int* __restrict__ flag) {
    __shared__ int snz[256];
    int i = threadIdx.x;
    snz[i] = e[2 * i + 1];
    __syncthreads();
    if (i == 0) {
        int nz = 0;
        for (int j = 0; j < 256; ++j) nz |= snz[j];
        *flag = (nz == 0) ? 1 : 0;
    }
}

__device__ __forceinline__ int edge_at(const int* e32, const long long* e64, int is64, long long idx) {
    return is64 ? (int)e64[idx] : e32[idx];
}

// ---------------- CSR build ----------------
__global__ void k_deg_count(const int* __restrict__ e, const int* __restrict__ flag,
                            int* __restrict__ cnt, int E) {
    int is64 = *flag;
    const long long* e64 = (const long long*)e;
    int i = blockIdx.x * blockDim.x + threadIdx.x;
    int stride = gridDim.x * blockDim.x;
    for (; i < E; i += stride) {
        int d = edge_at(e, e64, is64, (long long)E + i);
        atomicAdd(&cnt[d], 1);
    }
}

__global__ void k_dinv(const int* __restrict__ cnt, float* __restrict__ dinv, int n) {
    int i = blockIdx.x * blockDim.x + threadIdx.x;
    if (i < n) dinv[i] = rsqrtf((float)(cnt[i] + 1));
}

// padded row length: real edges + self loop, rounded up to 8
__device__ __forceinline__ int padlen(int c) { return (c + 8) & ~7; }

__global__ void k_chunk_sum(const int* __restrict__ cnt, int* __restrict__ bsum, int n) {
    __shared__ int sb[256];
    int base = blockIdx.x * SCAN_CHUNK;
    int s = 0;
    for (int j = threadIdx.x; j < SCAN_CHUNK; j += 256) {
        int i = base + j;
        if (i < n) s += padlen(cnt[i]);
    }
    sb[threadIdx.x] = s;
    __syncthreads();
    for (int off = 128; off > 0; off >>= 1) {
        if (threadIdx.x < off) sb[threadIdx.x] += sb[threadIdx.x + off];
        __syncthreads();
    }
    if (threadIdx.x == 0) bsum[blockIdx.x] = sb[0];
}

__global__ void k_scan_sums(const int* __restrict__ bsum, int* __restrict__ boff,
                            int* __restrict__ row_ptr, int nchunks, int n) {
    if (threadIdx.x == 0 && blockIdx.x == 0) {
        int run = 0;
        for (int b = 0; b < nchunks; ++b) { boff[b] = run; run += bsum[b]; }
        row_ptr[n] = run;
    }
}

__global__ void k_local_scan(const int* __restrict__ cnt, const int* __restrict__ boff,
                             int* __restrict__ row_ptr, int* __restrict__ cursor, int n) {
    __shared__ int sb[256];
    int tid = threadIdx.x;
    int base = blockIdx.x * SCAN_CHUNK + tid * 8;
    int v[8];
    int ts = 0;
#pragma unroll
    for (int j = 0; j < 8; ++j) {
        int i = base + j;
        v[j] = (i < n) ? padlen(cnt[i]) : 0;
        ts += v[j];
    }
    sb[tid] = ts;
    __syncthreads();
    for (int off = 1; off < 256; off <<= 1) {
        int t = (tid >= off) ? sb[tid - off] : 0;
        __syncthreads();
        sb[tid] += t;
        __syncthreads();
    }
    int excl = sb[tid] - ts + boff[blockIdx.x];
#pragma unroll
    for (int j = 0; j < 8; ++j) {
        int i = base + j;
        if (i < n) { row_ptr[i] = excl; cursor[i] = excl; }
        excl += v[j];
    }
}

// real edges scattered; src stored pre-shifted (<<6 = row offset in u32 units)
__global__ void k_fill(const int* __restrict__ e, const int* __restrict__ flag,
                       const float* __restrict__ dinv, int* __restrict__ cursor,
                       int2* __restrict__ ew, int E) {
    int is64 = *flag;
    const long long* e64 = (const long long*)e;
    int i = blockIdx.x * blockDim.x + threadIdx.x;
    int stride = gridDim.x * blockDim.x;
    for (; i < E; i += stride) {
        int s = edge_at(e, e64, is64, i);
        int d = edge_at(e, e64, is64, (long long)E + i);
        int pos = atomicAdd(&cursor[d], 1);
        ew[pos] = make_int2(s << 6, __float_as_int(dinv[s] * dinv[d]));
    }
}

// self-loop edge + zero-weight padding (points at own row -> cache-hot, contributes 0)
__global__ void k_pad(const int* __restrict__ cursor, const int* __restrict__ row_ptr,
                      const float* __restrict__ dinv, int2* __restrict__ ew, int n) {
    int i = blockIdx.x * blockDim.x + threadIdx.x;
    if (i >= n) return;
    int c = cursor[i];
    int end = row_ptr[i + 1];
    float di = dinv[i];
    ew[c] = make_int2(i << 6, __float_as_int(di * di));
    for (int p = c + 1; p < end; ++p) ew[p] = make_int2(i << 6, 0);
}

// ---------------- W prepack into MFMA B-fragment layout (raw bf16) ----------------
__global__ void k_prepack(const float* __restrict__ W1, const float* __restrict__ W2,
                          const float* __restrict__ W3, const float* __restrict__ Wl,
                          unsigned short* __restrict__ bp) {
    int job = blockIdx.x;
    const float* src;
    int rowoff = 0;
    if (job == 0) src = W1;
    else if (job == 1) src = W2;
    else if (job == 2) src = W3;
    else { src = Wl; rowoff = (job - 3) * 128; }
    unsigned short* dst = bp + job * 16384;
    for (int idx = threadIdx.x; idx < 16384; idx += 256) {
        int j = idx & 7, l = (idx >> 3) & 63, kt = (idx >> 9) & 3, nt = idx >> 11;
        int row = kt * 32 + (l >> 4) * 8 + j;
        int col = nt * 16 + (l & 15);
        dst[idx] = f2b(src[(rowoff + row) * 128 + col]);
    }
}

// ---------------- layer GEMM: zb = A @ Bp(+c), B in regs, wave-split by nt ----------------
// Each wave owns 2 column-tiles (nt = 2w, 2w+1) for a group of 4 row-tiles. No LDS/barriers.
template <int HAS_C, int A32>
__global__ __launch_bounds__(256) void k_gemm_z(const void* __restrict__ Av,
                                                const unsigned short* __restrict__ Bp,
                                                const float* __restrict__ cvec,
                                                unsigned short* __restrict__ zb, int n) {
    int tid = threadIdx.x;
    int l = tid & 63, w = tid >> 6;
    const short8* bp8 = (const short8*)Bp;
    short8 B[2][4];
#pragma unroll
    for (int i = 0; i < 2; ++i)
#pragma unroll
        for (int kt = 0; kt < 4; ++kt)
            B[i][kt] = bp8[((2 * w + i) * 4 + kt) * 64 + l];
    int kgrp = l >> 4, rit = l & 15, ccol = l & 15;
    int ntile = n >> 4;
    int t0 = blockIdx.x * 4;
    f32x4 acc[4][2];
#pragma unroll
    for (int tt = 0; tt < 4; ++tt) { acc[tt][0] = (f32x4)(0.f); acc[tt][1] = (f32x4)(0.f); }
#pragma unroll
    for (int kt = 0; kt < 4; ++kt) {
        short8 a[4];
#pragma unroll
        for (int tt = 0; tt < 4; ++tt) {
            int tile = min(t0 + tt, ntile - 1);
            size_t base = (size_t)(tile * 16 + rit) * 128 + kgrp * 8 + kt * 32;
            if (A32) {
                const float* a32 = (const float*)Av + base;
                float4 fa = *(const float4*)a32;
                float4 fb = *(const float4*)(a32 + 4);
                short8 af;
                af[0] = (short)f2b(fa.x); af[1] = (short)f2b(fa.y);
                af[2] = (short)f2b(fa.z); af[3] = (short)f2b(fa.w);
                af[4] = (short)f2b(fb.x); af[5] = (short)f2b(fb.y);
                af[6] = (short)f2b(fb.z); af[7] = (short)f2b(fb.w);
                a[tt] = af;
            } else {
                a[tt] = *(const short8*)((const unsigned short*)Av + base);
            }
        }
#pragma unroll
        for (int tt = 0; tt < 4; ++tt) {
            acc[tt][0] = __builtin_amdgcn_mfma_f32_16x16x32_bf16(a[tt], B[0][kt], acc[tt][0], 0, 0, 0);
            acc[tt][1] = __builtin_amdgcn_mfma_f32_16x16x32_bf16(a[tt], B[1][kt], acc[tt][1], 0, 0, 0);
        }
    }
    int crow0 = kgrp * 4;
    int col0 = 2 * w * 16 + ccol, col1 = col0 + 16;
    float cv0 = HAS_C ? cvec[col0] : 0.f;
    float cv1 = HAS_C ? cvec[col1] : 0.f;
#pragma unroll
    for (int tt = 0; tt < 4; ++tt) {
        int tile = t0 + tt;
        if (tile < ntile) {
            int r0 = tile * 16;
#pragma unroll
            for (int j = 0; j < 4; ++j) {
                int row = r0 + crow0 + j;
                zb[(size_t)row * 128 + col0] = f2b(acc[tt][0][j] + cv0);
                zb[(size_t)row * 128 + col1] = f2b(acc[tt][1][j] + cv1);
            }
        }
    }
}

// ---------------- CSR-pull aggregate + relu + BN stats (one node per wave) ----------------
// Padded rows (multiple of 8, self-loop included): pure load->fma inner loop, no tail.
__global__ __launch_bounds__(256) void k_agg(const unsigned short* __restrict__ zb,
                                             const int* __restrict__ row_ptr,
                                             const int2* __restrict__ ew,
                                             const float* __restrict__ bias,
                                             unsigned int* __restrict__ tb,
                                             float* __restrict__ stats64, int n) {
    int tid = threadIdx.x;
    int l = tid & 63, w = tid >> 6;
    int node = blockIdx.x * 4 + w;  // grid is exactly n/4 blocks
    const unsigned int* zl = (const unsigned int*)zb + l;
    float acc0 = bias[2 * l], acc1 = bias[2 * l + 1];
    int e0 = row_ptr[node], e1 = row_ptr[node + 1];
    int2 q[8];
#pragma unroll
    for (int j = 0; j < 8; ++j) q[j] = ew[e0 + j];
    int iters = (e1 - e0) >> 3;
    for (int it = 1; it <= iters; ++it) {
        unsigned int u[8];
        float wf[8];
#pragma unroll
        for (int j = 0; j < 8; ++j) {
            u[j] = zl[(unsigned int)q[j].x];
            wf[j] = __int_as_float(q[j].y);
        }
        int eb = e0 + it * 8;  // last iteration prefetches slack region (unused)
#pragma unroll
        for (int j = 0; j < 8; ++j) q[j] = ew[eb + j];
#pragma unroll
        for (int j = 0; j < 8; ++j) {
            acc0 = fmaf(wf[j], b2f_lo(u[j]), acc0);
            acc1 = fmaf(wf[j], b2f_hi(u[j]), acc1);
        }
    }
    acc0 = fmaxf(acc0, 0.f);
    acc1 = fmaxf(acc1, 0.f);
    tb[((size_t)node << 6) | l] = pack2(acc0, acc1);
    __shared__ float red[4][256];
    red[0][tid] = acc0; red[1][tid] = acc1;
    red[2][tid] = acc0 * acc0; red[3][tid] = acc1 * acc1;
    __syncthreads();
    int k = tid >> 6, li = tid & 63;
    float v = red[k][li] + red[k][64 + li] + red[k][128 + li] + red[k][192 + li];
    int f = 2 * li + (k & 1) + ((k >> 1) ? 128 : 0);
    atomicAdd(&stats64[(blockIdx.x & 63) * 256 + f], v);
}

// ---------------- fused BN finalize + shift-dots + B pre-scale ----------------
template <int MODE>
__global__ void k_bn_findots(const float* __restrict__ stats64,
                             const float* __restrict__ g, const float* __restrict__ be,
                             float invn, float* __restrict__ ss_out,
                             const float* __restrict__ Wn, float* __restrict__ cn,
                             const float* __restrict__ Wl, const float* __restrict__ base,
                             float* __restrict__ cl,
                             const unsigned short* __restrict__ bpn_src,
                             unsigned short* __restrict__ bpn_dst,
                             const unsigned short* __restrict__ bpl_src,
                             unsigned short* __restrict__ bpl_dst) {
    int tid = threadIdx.x;  // 256
    float a = 0.f;
#pragma unroll 8
    for (int c = 0; c < 64; ++c) a += stats64[c * 256 + tid];
    __shared__ float sums[256];
    __shared__ float sh[128];
    __shared__ float scs[128];
    sums[tid] = a;
    __syncthreads();
    if (tid < 128) {
        float m = sums[tid] * invn;
        float var = sums[128 + tid] * invn - m * m;
        float sc = g[tid] * rsqrtf(var + BN_EPS);
        scs[tid] = sc;
        sh[tid] = fmaf(-m, sc, be[tid]);
    }
    __syncthreads();
    if (blockIdx.x == 0 && tid < 128) {
        ss_out[tid] = scs[tid];
        ss_out[128 + tid] = sh[tid];
    }
    bool doCl = (MODE == 2) ? (blockIdx.x == 0) : (blockIdx.x == 1);
    bool doCn = (MODE < 2) && (blockIdx.x == 0);
    if (doCl || doCn) {
        const float* W = doCl ? Wl : Wn;
        int col = tid & 127, half = tid >> 7;
        float acc = 0.f;
#pragma unroll 4
        for (int k = half * 64; k < half * 64 + 64; ++k) acc = fmaf(sh[k], W[k * 128 + col], acc);
        __syncthreads();
        sums[tid] = acc;
        __syncthreads();
        if (tid < 128) {
            float tot = sums[tid] + sums[128 + tid];
            if (doCl) cl[tid] = ((MODE == 0) ? base[tid] : cl[tid]) + tot;
            else cn[tid] = tot;
        }
    }
    // scale prepacked B fragments by per-k scs
    int beg = blockIdx.x * 8192;
    if (MODE < 2) {
        for (int idx = beg + tid; idx < beg + 8192; idx += 256) {
            int k = ((idx >> 9) & 3) * 32 + ((idx >> 7) & 3) * 8 + (idx & 7);
            bpn_dst[idx] = f2b(us2f(bpn_src[idx]) * scs[k]);
        }
    }
    for (int idx = beg + tid; idx < beg + 8192; idx += 256) {
        int k = ((idx >> 9) & 3) * 32 + ((idx >> 7) & 3) * 8 + (idx & 7);
        bpl_dst[idx] = f2b(us2f(bpl_src[idx]) * scs[k]);
    }
}

// ---------------- final GEMM: out = relu([t1|t2|t3] @ BpL + cl), all-reg B ----------------
__global__ __launch_bounds__(256) void k_gemm_final(const unsigned short* __restrict__ t1,
                                                    const unsigned short* __restrict__ t2,
                                                    const unsigned short* __restrict__ t3,
                                                    const unsigned short* __restrict__ Bp,
                                                    const float* __restrict__ cl,
                                                    float* __restrict__ out, int n) {
    int tid = threadIdx.x;
    int l = tid & 63, w = tid >> 6;
    const short8* bp8 = (const short8*)Bp;
    short8 B[2][12];
#pragma unroll
    for (int b = 0; b < 3; ++b)
#pragma unroll
        for (int i = 0; i < 2; ++i)
#pragma unroll
            for (int kt = 0; kt < 4; ++kt)
                B[i][b * 4 + kt] = bp8[b * 2048 + ((2 * w + i) * 4 + kt) * 64 + l];
    int kgrp = l >> 4, rit = l & 15, ccol = l & 15;
    int ntile = n >> 4;
    int t0 = blockIdx.x * 4;
    f32x4 acc[4][2];
#pragma unroll
    for (int tt = 0; tt < 4; ++tt) { acc[tt][0] = (f32x4)(0.f); acc[tt][1] = (f32x4)(0.f); }
    const unsigned short* tbs[3] = {t1, t2, t3};
#pragma unroll
    for (int b = 0; b < 3; ++b) {
        const unsigned short* tp = tbs[b];
#pragma unroll
        for (int kt = 0; kt < 4; ++kt) {
            short8 a[4];
#pragma unroll
            for (int tt = 0; tt < 4; ++tt) {
                int tile = min(t0 + tt, ntile - 1);
                a[tt] = *(const short8*)(tp + (size_t)(tile * 16 + rit) * 128 + kgrp * 8 + kt * 32);
            }
#pragma unroll
            for (int tt = 0; tt < 4; ++tt) {
                acc[tt][0] = __builtin_amdgcn_mfma_f32_16x16x32_bf16(a[tt], B[0][b * 4 + kt], acc[tt][0], 0, 0, 0);
                acc[tt][1] = __builtin_amdgcn_mfma_f32_16x16x32_bf16(a[tt], B[1][b * 4 + kt], acc[tt][1], 0, 0, 0);
            }
        }
    }
    int crow0 = kgrp * 4;
    int col0 = 2 * w * 16 + ccol, col1 = col0 + 16;
    float cv0 = cl[col0], cv1 = cl[col1];
#pragma unroll
    for (int tt = 0; tt < 4; ++tt) {
        int tile = t0 + tt;
        if (tile < ntile) {
            int r0 = tile * 16;
#pragma unroll
            for (int j = 0; j < 4; ++j) {
                int row = r0 + crow0 + j;
                out[(size_t)row * 128 + col0] = fmaxf(acc[tt][0][j] + cv0, 0.f);
                out[(size_t)row * 128 + col1] = fmaxf(acc[tt][1][j] + cv1, 0.f);
            }
        }
    }
}

extern "C" void kernel_launch(void* const* d_in, const int* in_sizes, int n_in,
                              void* d_out, int out_size, void* d_ws, size_t ws_size,
                              hipStream_t stream) {
    const float* x   = (const float*)d_in[0];
    const int*   ei  = (const int*)d_in[1];
    const float* W1  = (const float*)d_in[3];
    const float* b1  = (const float*)d_in[4];
    const float* g1  = (const float*)d_in[5];
    const float* be1 = (const float*)d_in[6];
    const float* W2  = (const float*)d_in[7];
    const float* b2  = (const float*)d_in[8];
    const float* g2  = (const float*)d_in[9];
    const float* be2 = (const float*)d_in[10];
    const float* W3  = (const float*)d_in[11];
    const float* b3  = (const float*)d_in[12];
    const float* g3  = (const float*)d_in[13];
    const float* be3 = (const float*)d_in[14];
    const float* Wl  = (const float*)d_in[15];
    const float* bl  = (const float*)d_in[16];
    float* out = (float*)d_out;

    const int n = N_NODES;
    const int E = in_sizes[1] / 2;

    char* ws = (char*)d_ws;
    size_t off = 0;
    auto alloc = [&](size_t bytes) -> void* {
        void* p = ws + off;
        off += (bytes + 255) & ~((size_t)255);
        return p;
    };
    // zero-region: cnt + 3 striped stats buffers, contiguous, one memset
    int*            cnt     = (int*)alloc((size_t)n * 4);
    float*          st1     = (float*)alloc(64 * 256 * 4);
    float*          st2     = (float*)alloc(64 * 256 * 4);
    float*          st3     = (float*)alloc(64 * 256 * 4);
    size_t zero_bytes = (size_t)((char*)st3 + 64 * 256 * 4 - (char*)cnt);

    float*          dinv    = (float*)alloc((size_t)n * 4);
    int*            row_ptr = (int*)alloc((size_t)(n + 1) * 4);
    int*            cursor  = (int*)alloc((size_t)n * 4);
    int*            bsum    = (int*)alloc(64 * 4);
    int*            boff    = (int*)alloc(64 * 4);
    float*          ss1     = (float*)alloc(256 * 4);
    float*          ss2     = (float*)alloc(256 * 4);
    float*          ss3     = (float*)alloc(256 * 4);
    float*          c2      = (float*)alloc(128 * 4);
    float*          c3      = (float*)alloc(128 * 4);
    float*          cl      = (float*)alloc(128 * 4);
    int*            flag    = (int*)alloc(256);
    int2*           ew      = (int2*)alloc(((size_t)E + 8 * (size_t)n + 64) * 8);
    unsigned short* bp      = (unsigned short*)alloc(6 * 16384 * 2);   // raw prepack
    unsigned short* bpsN    = (unsigned short*)alloc(16384 * 2);       // scaled next-layer W
    unsigned short* bpsL    = (unsigned short*)alloc(3 * 16384 * 2);   // scaled Wl blocks
    unsigned short* zb      = (unsigned short*)alloc((size_t)n * 128 * 2);
    unsigned int*   tb1     = (unsigned int*)alloc((size_t)n * 64 * 4);
    unsigned int*   tb2     = (unsigned int*)alloc((size_t)n * 64 * 4);
    unsigned int*   tb3     = (unsigned int*)alloc((size_t)n * 64 * 4);

    hipMemsetAsync(cnt, 0, zero_bytes, stream);

    // ---- CSR build (padded rows) ----
    k_detect64<<<1, 256, 0, stream>>>(ei, flag);
    k_deg_count<<<512, 256, 0, stream>>>(ei, flag, cnt, E);
    k_dinv<<<(n + 255) / 256, 256, 0, stream>>>(cnt, dinv, n);
    int nchunks = (n + SCAN_CHUNK - 1) / SCAN_CHUNK;
    k_chunk_sum<<<nchunks, 256, 0, stream>>>(cnt, bsum, n);
    k_scan_sums<<<1, 32, 0, stream>>>(bsum, boff, row_ptr, nchunks, n);
    k_local_scan<<<nchunks, 256, 0, stream>>>(cnt, boff, row_ptr, cursor, n);
    k_fill<<<512, 256, 0, stream>>>(ei, flag, dinv, cursor, ew, E);
    k_pad<<<(n + 255) / 256, 256, 0, stream>>>(cursor, row_ptr, dinv, ew, n);

    k_prepack<<<6, 256, 0, stream>>>(W1, W2, W3, Wl, bp);

    const unsigned short* t1u = (const unsigned short*)tb1;
    const unsigned short* t2u = (const unsigned short*)tb2;
    const unsigned short* t3u = (const unsigned short*)tb3;
    float invn = 1.0f / n;
    int aggblk = n / 4;     // one node per wave
    int gemmblk = 782;      // ceil(3125 tiles / 4 tiles-per-block)

    // ---- layer 1 (reads x fp32 directly; raw W1) ----
    k_gemm_z<0, 1><<<gemmblk, 256, 0, stream>>>(x, bp, nullptr, zb, n);
    k_agg<<<aggblk, 256, 0, stream>>>(zb, row_ptr, ew, b1, tb1, st1, n);
    k_bn_findots<0><<<2, 256, 0, stream>>>(st1, g1, be1, invn, ss1, W2, c2, Wl, bl, cl,
                                           bp + 16384, bpsN, bp + 3 * 16384, bpsL);

    // ---- layer 2 (prescaled W2) ----
    k_gemm_z<1, 0><<<gemmblk, 256, 0, stream>>>(t1u, bpsN, c2, zb, n);
    k_agg<<<aggblk, 256, 0, stream>>>(zb, row_ptr, ew, b2, tb2, st2, n);
    k_bn_findots<1><<<2, 256, 0, stream>>>(st2, g2, be2, invn, ss2, W3, c3, Wl + 16384, nullptr, cl,
                                           bp + 2 * 16384, bpsN, bp + 4 * 16384, bpsL + 16384);

    // ---- layer 3 (prescaled W3) ----
    k_gemm_z<1, 0><<<gemmblk, 256, 0, stream>>>(t2u, bpsN, c3, zb, n);
    k_agg<<<aggblk, 256, 0, stream>>>(zb, row_ptr, ew, b3, tb3, st3, n);
    k_bn_findots<2><<<2, 256, 0, stream>>>(st3, g3, be3, invn, ss3, nullptr, nullptr,
                                           Wl + 2 * 16384, nullptr, cl,
                                           nullptr, nullptr, bp + 5 * 16384, bpsL + 2 * 16384);

    // ---- final fused GEMM over K=384 (prescaled Wl, all-reg B) ----
    k_gemm_final<<<gemmblk, 256, 0, stream>>>(t1u, t2u, t3u, bpsL, cl, out, n);
}

// Round 7
// 349.589 us; speedup vs baseline: 1.0243x; 1.0243x over previous
//
#include <hip/hip_runtime.h>

#define N_NODES 50000
#define BN_EPS 1e-5f
#define SCAN_CHUNK 2048

typedef __attribute__((ext_vector_type(8))) short short8;
typedef __attribute__((ext_vector_type(4))) float f32x4;

__device__ __forceinline__ unsigned short f2b(float x) {
    unsigned int u = __float_as_uint(x);
    unsigned int r = (u + 0x7fffu + ((u >> 16) & 1u)) >> 16;
    return (unsigned short)r;
}
__device__ __forceinline__ float b2f_lo(unsigned int u) { return __uint_as_float(u << 16); }
__device__ __forceinline__ float b2f_hi(unsigned int u) { return __uint_as_float(u & 0xffff0000u); }
__device__ __forceinline__ unsigned int pack2(float lo, float hi) {
    return (unsigned int)f2b(lo) | ((unsigned int)f2b(hi) << 16);
}
__device__ __forceinline__ float us2f(unsigned short s) {
    return __uint_as_float(((unsigned int)s) << 16);
}

// per-block int64 detection: odd 32-bit words of first 256 edge entries all zero <=> int64
__device__ __forceinline__ int detect_is64(const int* __restrict__ e, int tid) {
    __shared__ int snz[4];
    int lane = tid & 63, wv = tid >> 6;
    int v = e[2 * tid + 1];
    unsigned long long b = __ballot(v != 0);
    if (lane == 0) snz[wv] = (b != 0ULL) ? 1 : 0;
    __syncthreads();
    return !(snz[0] | snz[1] | snz[2] | snz[3]);
}

__device__ __forceinline__ int edge_at(const int* e32, const long long* e64, int is64, long long idx) {
    return is64 ? (int)e64[idx] : e32[idx];
}

// ---------------- CSR build ----------------
__global__ void k_deg_count(const int* __restrict__ e, int* __restrict__ cnt, int E) {
    int is64 = detect_is64(e, threadIdx.x);
    const long long* e64 = (const long long*)e;
    int i = blockIdx.x * blockDim.x + threadIdx.x;
    int stride = gridDim.x * blockDim.x;
    for (; i < E; i += stride) {
        int d = edge_at(e, e64, is64, (long long)E + i);
        atomicAdd(&cnt[d], 1);
    }
}

// padded row length: real edges + self loop, rounded up to 8
__device__ __forceinline__ int padlen(int c) { return (c + 8) & ~7; }

// chunk sums of padded lengths + dinv computation (fused)
__global__ void k_chunk_dinv(const int* __restrict__ cnt, int* __restrict__ bsum,
                             float* __restrict__ dinv, int n) {
    __shared__ int sb[256];
    int base = blockIdx.x * SCAN_CHUNK;
    int s = 0;
    for (int j = threadIdx.x; j < SCAN_CHUNK; j += 256) {
        int i = base + j;
        if (i < n) {
            int c = cnt[i];
            s += padlen(c);
            dinv[i] = rsqrtf((float)(c + 1));
        }
    }
    sb[threadIdx.x] = s;
    __syncthreads();
    for (int off = 128; off > 0; off >>= 1) {
        if (threadIdx.x < off) sb[threadIdx.x] += sb[threadIdx.x + off];
        __syncthreads();
    }
    if (threadIdx.x == 0) bsum[blockIdx.x] = sb[0];
}

// local exclusive scan; each block computes its own chunk offset from bsum (nchunks small)
__global__ void k_local_scan(const int* __restrict__ cnt, const int* __restrict__ bsum,
                             int* __restrict__ row_ptr, int* __restrict__ cursor,
                             int n, int nchunks) {
    __shared__ int sb[256];
    __shared__ int base_off;
    int tid = threadIdx.x;
    if (tid == 0) {
        int run = 0;
        for (int b = 0; b < blockIdx.x; ++b) run += bsum[b];
        base_off = run;
        if (blockIdx.x == gridDim.x - 1) {
            int tot = run;
            for (int b = blockIdx.x; b < nchunks; ++b) tot += bsum[b];
            row_ptr[n] = tot;
        }
    }
    int base = blockIdx.x * SCAN_CHUNK + tid * 8;
    int v[8];
    int ts = 0;
#pragma unroll
    for (int j = 0; j < 8; ++j) {
        int i = base + j;
        v[j] = (i < n) ? padlen(cnt[i]) : 0;
        ts += v[j];
    }
    sb[tid] = ts;
    __syncthreads();
    for (int off = 1; off < 256; off <<= 1) {
        int t = (tid >= off) ? sb[tid - off] : 0;
        __syncthreads();
        sb[tid] += t;
        __syncthreads();
    }
    int excl = sb[tid] - ts + base_off;
#pragma unroll
    for (int j = 0; j < 8; ++j) {
        int i = base + j;
        if (i < n) { row_ptr[i] = excl; cursor[i] = excl; }
        excl += v[j];
    }
}

// real edges scattered; src stored pre-shifted (<<6 = row offset in u32 units)
__global__ void k_fill(const int* __restrict__ e, const float* __restrict__ dinv,
                       int* __restrict__ cursor, int2* __restrict__ ew, int E) {
    int is64 = detect_is64(e, threadIdx.x);
    const long long* e64 = (const long long*)e;
    int i = blockIdx.x * blockDim.x + threadIdx.x;
    int stride = gridDim.x * blockDim.x;
    for (; i < E; i += stride) {
        int s = edge_at(e, e64, is64, i);
        int d = edge_at(e, e64, is64, (long long)E + i);
        int pos = atomicAdd(&cursor[d], 1);
        ew[pos] = make_int2(s << 6, __float_as_int(dinv[s] * dinv[d]));
    }
}

// self-loop edge + zero-weight padding (points at own row -> cache-hot, contributes 0)
__global__ void k_pad(const int* __restrict__ cursor, const int* __restrict__ row_ptr,
                      const float* __restrict__ dinv, int2* __restrict__ ew, int n) {
    int i = blockIdx.x * blockDim.x + threadIdx.x;
    if (i >= n) return;
    int c = cursor[i];
    int end = row_ptr[i + 1];
    float di = dinv[i];
    ew[c] = make_int2(i << 6, __float_as_int(di * di));
    for (int p = c + 1; p < end; ++p) ew[p] = make_int2(i << 6, 0);
}

// ---------------- W prepack into MFMA B-fragment layout (raw bf16) ----------------
__global__ void k_prepack(const float* __restrict__ W1, const float* __restrict__ W2,
                          const float* __restrict__ W3, const float* __restrict__ Wl,
                          unsigned short* __restrict__ bp) {
    int job = blockIdx.x;
    const float* src;
    int rowoff = 0;
    if (job == 0) src = W1;
    else if (job == 1) src = W2;
    else if (job == 2) src = W3;
    else { src = Wl; rowoff = (job - 3) * 128; }
    unsigned short* dst = bp + job * 16384;
    for (int idx = threadIdx.x; idx < 16384; idx += 256) {
        int j = idx & 7, l = (idx >> 3) & 63, kt = (idx >> 9) & 3, nt = idx >> 11;
        int row = kt * 32 + (l >> 4) * 8 + j;
        int col = nt * 16 + (l & 15);
        dst[idx] = f2b(src[(rowoff + row) * 128 + col]);
    }
}

// ---------------- layer GEMM: zb = A @ Bp(+c), B in regs, persistent blocks ----------------
// Each wave owns 2 column-tiles (nt = 2w, 2w+1); block loops over groups of 4 row-tiles.
template <int HAS_C, int A32>
__global__ __launch_bounds__(256) void k_gemm_z(const void* __restrict__ Av,
                                                const unsigned short* __restrict__ Bp,
                                                const float* __restrict__ cvec,
                                                unsigned short* __restrict__ zb, int n) {
    int tid = threadIdx.x;
    int l = tid & 63, w = tid >> 6;
    const short8* bp8 = (const short8*)Bp;
    short8 B[2][4];
#pragma unroll
    for (int i = 0; i < 2; ++i)
#pragma unroll
        for (int kt = 0; kt < 4; ++kt)
            B[i][kt] = bp8[((2 * w + i) * 4 + kt) * 64 + l];
    int kgrp = l >> 4, rit = l & 15, ccol = l & 15;
    int ntile = n >> 4;
    int col0 = 2 * w * 16 + ccol, col1 = col0 + 16;
    float cv0 = HAS_C ? cvec[col0] : 0.f;
    float cv1 = HAS_C ? cvec[col1] : 0.f;
    for (int t0 = blockIdx.x * 4; t0 < ntile; t0 += gridDim.x * 4) {
        f32x4 acc[4][2];
#pragma unroll
        for (int tt = 0; tt < 4; ++tt) { acc[tt][0] = (f32x4)(0.f); acc[tt][1] = (f32x4)(0.f); }
#pragma unroll
        for (int kt = 0; kt < 4; ++kt) {
            short8 a[4];
#pragma unroll
            for (int tt = 0; tt < 4; ++tt) {
                int tile = min(t0 + tt, ntile - 1);
                size_t base = (size_t)(tile * 16 + rit) * 128 + kgrp * 8 + kt * 32;
                if (A32) {
                    const float* a32 = (const float*)Av + base;
                    float4 fa = *(const float4*)a32;
                    float4 fb = *(const float4*)(a32 + 4);
                    short8 af;
                    af[0] = (short)f2b(fa.x); af[1] = (short)f2b(fa.y);
                    af[2] = (short)f2b(fa.z); af[3] = (short)f2b(fa.w);
                    af[4] = (short)f2b(fb.x); af[5] = (short)f2b(fb.y);
                    af[6] = (short)f2b(fb.z); af[7] = (short)f2b(fb.w);
                    a[tt] = af;
                } else {
                    a[tt] = *(const short8*)((const unsigned short*)Av + base);
                }
            }
#pragma unroll
            for (int tt = 0; tt < 4; ++tt) {
                acc[tt][0] = __builtin_amdgcn_mfma_f32_16x16x32_bf16(a[tt], B[0][kt], acc[tt][0], 0, 0, 0);
                acc[tt][1] = __builtin_amdgcn_mfma_f32_16x16x32_bf16(a[tt], B[1][kt], acc[tt][1], 0, 0, 0);
            }
        }
        int crow0 = kgrp * 4;
#pragma unroll
        for (int tt = 0; tt < 4; ++tt) {
            int tile = t0 + tt;
            if (tile < ntile) {
                int r0 = tile * 16;
#pragma unroll
                for (int j = 0; j < 4; ++j) {
                    int row = r0 + crow0 + j;
                    zb[(size_t)row * 128 + col0] = f2b(acc[tt][0][j] + cv0);
                    zb[(size_t)row * 128 + col1] = f2b(acc[tt][1][j] + cv1);
                }
            }
        }
    }
}

// ---------------- CSR-pull aggregate + relu + BN stats (one node per wave) ----------------
__global__ __launch_bounds__(256) void k_agg(const unsigned short* __restrict__ zb,
                                             const int* __restrict__ row_ptr,
                                             const int2* __restrict__ ew,
                                             const float* __restrict__ bias,
                                             unsigned int* __restrict__ tb,
                                             float* __restrict__ stats64, int n) {
    int tid = threadIdx.x;
    int l = tid & 63, w = tid >> 6;
    int node = blockIdx.x * 4 + w;  // grid is exactly n/4 blocks
    const unsigned int* zl = (const unsigned int*)zb + l;
    float acc0 = bias[2 * l], acc1 = bias[2 * l + 1];
    int e0 = row_ptr[node], e1 = row_ptr[node + 1];
    int2 q[8];
#pragma unroll
    for (int j = 0; j < 8; ++j) q[j] = ew[e0 + j];
    int iters = (e1 - e0) >> 3;
    for (int it = 1; it <= iters; ++it) {
        unsigned int u[8];
        float wf[8];
#pragma unroll
        for (int j = 0; j < 8; ++j) {
            u[j] = zl[(unsigned int)q[j].x];
            wf[j] = __int_as_float(q[j].y);
        }
        int eb = e0 + it * 8;  // last iteration prefetches slack region (unused)
#pragma unroll
        for (int j = 0; j < 8; ++j) q[j] = ew[eb + j];
#pragma unroll
        for (int j = 0; j < 8; ++j) {
            acc0 = fmaf(wf[j], b2f_lo(u[j]), acc0);
            acc1 = fmaf(wf[j], b2f_hi(u[j]), acc1);
        }
    }
    acc0 = fmaxf(acc0, 0.f);
    acc1 = fmaxf(acc1, 0.f);
    tb[((size_t)node << 6) | l] = pack2(acc0, acc1);
    __shared__ float red[4][256];
    red[0][tid] = acc0; red[1][tid] = acc1;
    red[2][tid] = acc0 * acc0; red[3][tid] = acc1 * acc1;
    __syncthreads();
    int k = tid >> 6, li = tid & 63;
    float v = red[k][li] + red[k][64 + li] + red[k][128 + li] + red[k][192 + li];
    int f = 2 * li + (k & 1) + ((k >> 1) ? 128 : 0);
    atomicAdd(&stats64[(blockIdx.x & 63) * 256 + f], v);
}

// ---------------- fused BN finalize + shift-dots + B pre-scale ----------------
template <int MODE>
__global__ void k_bn_findots(const float* __restrict__ stats64,
                             const float* __restrict__ g, const float* __restrict__ be,
                             float invn, float* __restrict__ ss_out,
                             const float* __restrict__ Wn, float* __restrict__ cn,
                             const float* __restrict__ Wl, const float* __restrict__ base,
                             float* __restrict__ cl,
                             const unsigned short* __restrict__ bpn_src,
                             unsigned short* __restrict__ bpn_dst,
                             const unsigned short* __restrict__ bpl_src,
                             unsigned short* __restrict__ bpl_dst) {
    int tid = threadIdx.x;  // 256
    float a = 0.f;
#pragma unroll 8
    for (int c = 0; c < 64; ++c) a += stats64[c * 256 + tid];
    __shared__ float sums[256];
    __shared__ float sh[128];
    __shared__ float scs[128];
    sums[tid] = a;
    __syncthreads();
    if (tid < 128) {
        float m = sums[tid] * invn;
        float var = sums[128 + tid] * invn - m * m;
        float sc = g[tid] * rsqrtf(var + BN_EPS);
        scs[tid] = sc;
        sh[tid] = fmaf(-m, sc, be[tid]);
    }
    __syncthreads();
    if (blockIdx.x == 0 && tid < 128) {
        ss_out[tid] = scs[tid];
        ss_out[128 + tid] = sh[tid];
    }
    bool doCl = (MODE == 2) ? (blockIdx.x == 0) : (blockIdx.x == 1);
    bool doCn = (MODE < 2) && (blockIdx.x == 0);
    if (doCl || doCn) {
        const float* W = doCl ? Wl : Wn;
        int col = tid & 127, half = tid >> 7;
        float acc = 0.f;
#pragma unroll 4
        for (int k = half * 64; k < half * 64 + 64; ++k) acc = fmaf(sh[k], W[k * 128 + col], acc);
        __syncthreads();
        sums[tid] = acc;
        __syncthreads();
        if (tid < 128) {
            float tot = sums[tid] + sums[128 + tid];
            if (doCl) cl[tid] = ((MODE == 0) ? base[tid] : cl[tid]) + tot;
            else cn[tid] = tot;
        }
    }
    // scale prepacked B fragments by per-k scs
    int beg = blockIdx.x * 8192;
    if (MODE < 2) {
        for (int idx = beg + tid; idx < beg + 8192; idx += 256) {
            int k = ((idx >> 9) & 3) * 32 + ((idx >> 7) & 3) * 8 + (idx & 7);
            bpn_dst[idx] = f2b(us2f(bpn_src[idx]) * scs[k]);
        }
    }
    for (int idx = beg + tid; idx < beg + 8192; idx += 256) {
        int k = ((idx >> 9) & 3) * 32 + ((idx >> 7) & 3) * 8 + (idx & 7);
        bpl_dst[idx] = f2b(us2f(bpl_src[idx]) * scs[k]);
    }
}

// ---------------- final GEMM: out = relu([t1|t2|t3] @ BpL + cl), all-reg B, persistent ----------------
__global__ __launch_bounds__(256) void k_gemm_final(const unsigned short* __restrict__ t1,
                                                    const unsigned short* __restrict__ t2,
                                                    const unsigned short* __restrict__ t3,
                                                    const unsigned short* __restrict__ Bp,
                                                    const float* __restrict__ cl,
                                                    float* __restrict__ out, int n) {
    int tid = threadIdx.x;
    int l = tid & 63, w = tid >> 6;
    const short8* bp8 = (const short8*)Bp;
    short8 B[2][12];
#pragma unroll
    for (int b = 0; b < 3; ++b)
#pragma unroll
        for (int i = 0; i < 2; ++i)
#pragma unroll
            for (int kt = 0; kt < 4; ++kt)
                B[i][b * 4 + kt] = bp8[b * 2048 + ((2 * w + i) * 4 + kt) * 64 + l];
    int kgrp = l >> 4, rit = l & 15, ccol = l & 15;
    int ntile = n >> 4;
    int col0 = 2 * w * 16 + ccol, col1 = col0 + 16;
    float cv0 = cl[col0], cv1 = cl[col1];
    const unsigned short* tbs[3] = {t1, t2, t3};
    for (int t0 = blockIdx.x * 4; t0 < ntile; t0 += gridDim.x * 4) {
        f32x4 acc[4][2];
#pragma unroll
        for (int tt = 0; tt < 4; ++tt) { acc[tt][0] = (f32x4)(0.f); acc[tt][1] = (f32x4)(0.f); }
#pragma unroll
        for (int b = 0; b < 3; ++b) {
            const unsigned short* tp = tbs[b];
#pragma unroll
            for (int kt = 0; kt < 4; ++kt) {
                short8 a[4];
#pragma unroll
                for (int tt = 0; tt < 4; ++tt) {
                    int tile = min(t0 + tt, ntile - 1);
                    a[tt] = *(const short8*)(tp + (size_t)(tile * 16 + rit) * 128 + kgrp * 8 + kt * 32);
                }
#pragma unroll
                for (int tt = 0; tt < 4; ++tt) {
                    acc[tt][0] = __builtin_amdgcn_mfma_f32_16x16x32_bf16(a[tt], B[0][b * 4 + kt], acc[tt][0], 0, 0, 0);
                    acc[tt][1] = __builtin_amdgcn_mfma_f32_16x16x32_bf16(a[tt], B[1][b * 4 + kt], acc[tt][1], 0, 0, 0);
                }
            }
        }
        int crow0 = kgrp * 4;
#pragma unroll
        for (int tt = 0; tt < 4; ++tt) {
            int tile = t0 + tt;
            if (tile < ntile) {
                int r0 = tile * 16;
#pragma unroll
                for (int j = 0; j < 4; ++j) {
                    int row = r0 + crow0 + j;
                    out[(size_t)row * 128 + col0] = fmaxf(acc[tt][0][j] + cv0, 0.f);
                    out[(size_t)row * 128 + col1] = fmaxf(acc[tt][1][j] + cv1, 0.f);
                }
            }
        }
    }
}

extern "C" void kernel_launch(void* const* d_in, const int* in_sizes, int n_in,
                              void* d_out, int out_size, void* d_ws, size_t ws_size,
                              hipStream_t stream) {
    const float* x   = (const float*)d_in[0];
    const int*   ei  = (const int*)d_in[1];
    const float* W1  = (const float*)d_in[3];
    const float* b1  = (const float*)d_in[4];
    const float* g1  = (const float*)d_in[5];
    const float* be1 = (const float*)d_in[6];
    const float* W2  = (const float*)d_in[7];
    const float* b2  = (const float*)d_in[8];
    const float* g2  = (const float*)d_in[9];
    const float* be2 = (const float*)d_in[10];
    const float* W3  = (const float*)d_in[11];
    const float* b3  = (const float*)d_in[12];
    const float* g3  = (const float*)d_in[13];
    const float* be3 = (const float*)d_in[14];
    const float* Wl  = (const float*)d_in[15];
    const float* bl  = (const float*)d_in[16];
    float* out = (float*)d_out;

    const int n = N_NODES;
    const int E = in_sizes[1] / 2;

    char* ws = (char*)d_ws;
    size_t off = 0;
    auto alloc = [&](size_t bytes) -> void* {
        void* p = ws + off;
        off += (bytes + 255) & ~((size_t)255);
        return p;
    };
    // zero-region: cnt + 3 striped stats buffers, contiguous, one memset
    int*            cnt     = (int*)alloc((size_t)n * 4);
    float*          st1     = (float*)alloc(64 * 256 * 4);
    float*          st2     = (float*)alloc(64 * 256 * 4);
    float*          st3     = (float*)alloc(64 * 256 * 4);
    size_t zero_bytes = (size_t)((char*)st3 + 64 * 256 * 4 - (char*)cnt);

    float*          dinv    = (float*)alloc((size_t)n * 4);
    int*            row_ptr = (int*)alloc((size_t)(n + 1) * 4);
    int*            cursor  = (int*)alloc((size_t)n * 4);
    int*            bsum    = (int*)alloc(64 * 4);
    float*          ss1     = (float*)alloc(256 * 4);
    float*          ss2     = (float*)alloc(256 * 4);
    float*          ss3     = (float*)alloc(256 * 4);
    float*          c2      = (float*)alloc(128 * 4);
    float*          c3      = (float*)alloc(128 * 4);
    float*          cl      = (float*)alloc(128 * 4);
    int2*           ew      = (int2*)alloc(((size_t)E + 8 * (size_t)n + 64) * 8);
    unsigned short* bp      = (unsigned short*)alloc(6 * 16384 * 2);   // raw prepack
    unsigned short* bpsN    = (unsigned short*)alloc(16384 * 2);       // scaled next-layer W
    unsigned short* bpsL    = (unsigned short*)alloc(3 * 16384 * 2);   // scaled Wl blocks
    unsigned short* zb      = (unsigned short*)alloc((size_t)n * 128 * 2);
    unsigned int*   tb1     = (unsigned int*)alloc((size_t)n * 64 * 4);
    unsigned int*   tb2     = (unsigned int*)alloc((size_t)n * 64 * 4);
    unsigned int*   tb3     = (unsigned int*)alloc((size_t)n * 64 * 4);

    hipMemsetAsync(cnt, 0, zero_bytes, stream);

    // ---- CSR build (padded rows) ----
    k_deg_count<<<2048, 256, 0, stream>>>(ei, cnt, E);
    int nchunks = (n + SCAN_CHUNK - 1) / SCAN_CHUNK;
    k_chunk_dinv<<<nchunks, 256, 0, stream>>>(cnt, bsum, dinv, n);
    k_local_scan<<<nchunks, 256, 0, stream>>>(cnt, bsum, row_ptr, cursor, n, nchunks);
    k_fill<<<2048, 256, 0, stream>>>(ei, dinv, cursor, ew, E);
    k_pad<<<(n + 255) / 256, 256, 0, stream>>>(cursor, row_ptr, dinv, ew, n);

    k_prepack<<<6, 256, 0, stream>>>(W1, W2, W3, Wl, bp);

    const unsigned short* t1u = (const unsigned short*)tb1;
    const unsigned short* t2u = (const unsigned short*)tb2;
    const unsigned short* t3u = (const unsigned short*)tb3;
    float invn = 1.0f / n;
    int aggblk = n / 4;     // one node per wave
    int gemmblk = 391;      // persistent: 2 groups of 4 tiles per block

    // ---- layer 1 (reads x fp32 directly; raw W1) ----
    k_gemm_z<0, 1><<<gemmblk, 256, 0, stream>>>(x, bp, nullptr, zb, n);
    k_agg<<<aggblk, 256, 0, stream>>>(zb, row_ptr, ew, b1, tb1, st1, n);
    k_bn_findots<0><<<2, 256, 0, stream>>>(st1, g1, be1, invn, ss1, W2, c2, Wl, bl, cl,
                                           bp + 16384, bpsN, bp + 3 * 16384, bpsL);

    // ---- layer 2 (prescaled W2) ----
    k_gemm_z<1, 0><<<gemmblk, 256, 0, stream>>>(t1u, bpsN, c2, zb, n);
    k_agg<<<aggblk, 256, 0, stream>>>(zb, row_ptr, ew, b2, tb2, st2, n);
    k_bn_findots<1><<<2, 256, 0, stream>>>(st2, g2, be2, invn, ss2, W3, c3, Wl + 16384, nullptr, cl,
                                           bp + 2 * 16384, bpsN, bp + 4 * 16384, bpsL + 16384);

    // ---- layer 3 (prescaled W3) ----
    k_gemm_z<1, 0><<<gemmblk, 256, 0, stream>>>(t2u, bpsN, c3, zb, n);
    k_agg<<<aggblk, 256, 0, stream>>>(zb, row_ptr, ew, b3, tb3, st3, n);
    k_bn_findots<2><<<2, 256, 0, stream>>>(st3, g3, be3, invn, ss3, nullptr, nullptr,
                                           Wl + 2 * 16384, nullptr, cl,
                                           nullptr, nullptr, bp + 5 * 16384, bpsL + 2 * 16384);

    // ---- final fused GEMM over K=384 (prescaled Wl, all-reg B) ----
    k_gemm_final<<<gemmblk, 256, 0, stream>>>(t1u, t2u, t3u, bpsL, cl, out, n);
}

// Round 8
// 343.397 us; speedup vs baseline: 1.0427x; 1.0180x over previous
//
#include <hip/hip_runtime.h>
#include <hip/hip_fp16.h>

#define N_NODES 50000
#define BN_EPS 1e-5f
#define SCAN_CHUNK 2048

typedef __attribute__((ext_vector_type(8))) short short8;
typedef __attribute__((ext_vector_type(4))) float f32x4;

__device__ __forceinline__ unsigned short f2b(float x) {
    unsigned int u = __float_as_uint(x);
    unsigned int r = (u + 0x7fffu + ((u >> 16) & 1u)) >> 16;
    return (unsigned short)r;
}
__device__ __forceinline__ float b2f_lo(unsigned int u) { return __uint_as_float(u << 16); }
__device__ __forceinline__ float b2f_hi(unsigned int u) { return __uint_as_float(u & 0xffff0000u); }
__device__ __forceinline__ unsigned int pack2(float lo, float hi) {
    return (unsigned int)f2b(lo) | ((unsigned int)f2b(hi) << 16);
}
__device__ __forceinline__ float us2f(unsigned short s) {
    return __uint_as_float(((unsigned int)s) << 16);
}
// edge record: src node in high 16 bits, fp16 weight in low 16 bits
__device__ __forceinline__ unsigned int pack_edge(int s, float w) {
    return ((unsigned int)s << 16) | (unsigned int)__half_as_ushort(__float2half(w));
}

// per-block int64 detection: odd 32-bit words of first 256 edge entries all zero <=> int64
__device__ __forceinline__ int detect_is64(const int* __restrict__ e, int tid) {
    __shared__ int snz[4];
    int lane = tid & 63, wv = tid >> 6;
    int v = e[2 * tid + 1];
    unsigned long long b = __ballot(v != 0);
    if (lane == 0) snz[wv] = (b != 0ULL) ? 1 : 0;
    __syncthreads();
    return !(snz[0] | snz[1] | snz[2] | snz[3]);
}

__device__ __forceinline__ int edge_at(const int* e32, const long long* e64, int is64, long long idx) {
    return is64 ? (int)e64[idx] : e32[idx];
}

// ---------------- CSR build ----------------
__global__ void k_deg_count(const int* __restrict__ e, int* __restrict__ cnt, int E) {
    int is64 = detect_is64(e, threadIdx.x);
    const long long* e64 = (const long long*)e;
    int i = blockIdx.x * blockDim.x + threadIdx.x;
    int stride = gridDim.x * blockDim.x;
    for (; i < E; i += stride) {
        int d = edge_at(e, e64, is64, (long long)E + i);
        atomicAdd(&cnt[d], 1);
    }
}

// padded row length: real edges + self loop, rounded up to 8
__device__ __forceinline__ int padlen(int c) { return (c + 8) & ~7; }

// chunk sums of padded lengths + dinv computation (fused)
__global__ void k_chunk_dinv(const int* __restrict__ cnt, int* __restrict__ bsum,
                             float* __restrict__ dinv, int n) {
    __shared__ int sb[256];
    int base = blockIdx.x * SCAN_CHUNK;
    int s = 0;
    for (int j = threadIdx.x; j < SCAN_CHUNK; j += 256) {
        int i = base + j;
        if (i < n) {
            int c = cnt[i];
            s += padlen(c);
            dinv[i] = rsqrtf((float)(c + 1));
        }
    }
    sb[threadIdx.x] = s;
    __syncthreads();
    for (int off = 128; off > 0; off >>= 1) {
        if (threadIdx.x < off) sb[threadIdx.x] += sb[threadIdx.x + off];
        __syncthreads();
    }
    if (threadIdx.x == 0) bsum[blockIdx.x] = sb[0];
}

// local exclusive scan; each block computes its own chunk offset from bsum (nchunks small)
__global__ void k_local_scan(const int* __restrict__ cnt, const int* __restrict__ bsum,
                             int* __restrict__ row_ptr, int* __restrict__ cursor,
                             int n, int nchunks) {
    __shared__ int sb[256];
    __shared__ int base_off;
    int tid = threadIdx.x;
    if (tid == 0) {
        int run = 0;
        for (int b = 0; b < blockIdx.x; ++b) run += bsum[b];
        base_off = run;
        if (blockIdx.x == gridDim.x - 1) {
            int tot = run;
            for (int b = blockIdx.x; b < nchunks; ++b) tot += bsum[b];
            row_ptr[n] = tot;
        }
    }
    int base = blockIdx.x * SCAN_CHUNK + tid * 8;
    int v[8];
    int ts = 0;
#pragma unroll
    for (int j = 0; j < 8; ++j) {
        int i = base + j;
        v[j] = (i < n) ? padlen(cnt[i]) : 0;
        ts += v[j];
    }
    sb[tid] = ts;
    __syncthreads();
    for (int off = 1; off < 256; off <<= 1) {
        int t = (tid >= off) ? sb[tid - off] : 0;
        __syncthreads();
        sb[tid] += t;
        __syncthreads();
    }
    int excl = sb[tid] - ts + base_off;
#pragma unroll
    for (int j = 0; j < 8; ++j) {
        int i = base + j;
        if (i < n) { row_ptr[i] = excl; cursor[i] = excl; }
        excl += v[j];
    }
}

// real edges scattered into 4B records (src:16 | f16 weight:16)
__global__ void k_fill(const int* __restrict__ e, const float* __restrict__ dinv,
                       int* __restrict__ cursor, unsigned int* __restrict__ ew, int E) {
    int is64 = detect_is64(e, threadIdx.x);
    const long long* e64 = (const long long*)e;
    int i = blockIdx.x * blockDim.x + threadIdx.x;
    int stride = gridDim.x * blockDim.x;
    for (; i < E; i += stride) {
        int s = edge_at(e, e64, is64, i);
        int d = edge_at(e, e64, is64, (long long)E + i);
        int pos = atomicAdd(&cursor[d], 1);
        ew[pos] = pack_edge(s, dinv[s] * dinv[d]);
    }
}

// self-loop edge + zero-weight padding (points at own row -> cache-hot, contributes 0)
__global__ void k_pad(const int* __restrict__ cursor, const int* __restrict__ row_ptr,
                      const float* __restrict__ dinv, unsigned int* __restrict__ ew, int n) {
    int i = blockIdx.x * blockDim.x + threadIdx.x;
    if (i >= n) return;
    int c = cursor[i];
    int end = row_ptr[i + 1];
    float di = dinv[i];
    ew[c] = pack_edge(i, di * di);
    unsigned int padv = (unsigned int)i << 16;  // weight f16 zero
    for (int p = c + 1; p < end; ++p) ew[p] = padv;
}

// ---------------- W prepack into MFMA B-fragment layout (raw bf16) ----------------
__global__ void k_prepack(const float* __restrict__ W1, const float* __restrict__ W2,
                          const float* __restrict__ W3, const float* __restrict__ Wl,
                          unsigned short* __restrict__ bp) {
    int job = blockIdx.x;
    const float* src;
    int rowoff = 0;
    if (job == 0) src = W1;
    else if (job == 1) src = W2;
    else if (job == 2) src = W3;
    else { src = Wl; rowoff = (job - 3) * 128; }
    unsigned short* dst = bp + job * 16384;
    for (int idx = threadIdx.x; idx < 16384; idx += 256) {
        int j = idx & 7, l = (idx >> 3) & 63, kt = (idx >> 9) & 3, nt = idx >> 11;
        int row = kt * 32 + (l >> 4) * 8 + j;
        int col = nt * 16 + (l & 15);
        dst[idx] = f2b(src[(rowoff + row) * 128 + col]);
    }
}

// ---------------- layer GEMM: zb = A @ Bp(+c), B in regs, persistent blocks ----------------
template <int HAS_C, int A32>
__global__ __launch_bounds__(256) void k_gemm_z(const void* __restrict__ Av,
                                                const unsigned short* __restrict__ Bp,
                                                const float* __restrict__ cvec,
                                                unsigned short* __restrict__ zb, int n) {
    int tid = threadIdx.x;
    int l = tid & 63, w = tid >> 6;
    const short8* bp8 = (const short8*)Bp;
    short8 B[2][4];
#pragma unroll
    for (int i = 0; i < 2; ++i)
#pragma unroll
        for (int kt = 0; kt < 4; ++kt)
            B[i][kt] = bp8[((2 * w + i) * 4 + kt) * 64 + l];
    int kgrp = l >> 4, rit = l & 15, ccol = l & 15;
    int ntile = n >> 4;
    int col0 = 2 * w * 16 + ccol, col1 = col0 + 16;
    float cv0 = HAS_C ? cvec[col0] : 0.f;
    float cv1 = HAS_C ? cvec[col1] : 0.f;
    for (int t0 = blockIdx.x * 4; t0 < ntile; t0 += gridDim.x * 4) {
        f32x4 acc[4][2];
#pragma unroll
        for (int tt = 0; tt < 4; ++tt) { acc[tt][0] = (f32x4)(0.f); acc[tt][1] = (f32x4)(0.f); }
#pragma unroll
        for (int kt = 0; kt < 4; ++kt) {
            short8 a[4];
#pragma unroll
            for (int tt = 0; tt < 4; ++tt) {
                int tile = min(t0 + tt, ntile - 1);
                size_t base = (size_t)(tile * 16 + rit) * 128 + kgrp * 8 + kt * 32;
                if (A32) {
                    const float* a32 = (const float*)Av + base;
                    float4 fa = *(const float4*)a32;
                    float4 fb = *(const float4*)(a32 + 4);
                    short8 af;
                    af[0] = (short)f2b(fa.x); af[1] = (short)f2b(fa.y);
                    af[2] = (short)f2b(fa.z); af[3] = (short)f2b(fa.w);
                    af[4] = (short)f2b(fb.x); af[5] = (short)f2b(fb.y);
                    af[6] = (short)f2b(fb.z); af[7] = (short)f2b(fb.w);
                    a[tt] = af;
                } else {
                    a[tt] = *(const short8*)((const unsigned short*)Av + base);
                }
            }
#pragma unroll
            for (int tt = 0; tt < 4; ++tt) {
                acc[tt][0] = __builtin_amdgcn_mfma_f32_16x16x32_bf16(a[tt], B[0][kt], acc[tt][0], 0, 0, 0);
                acc[tt][1] = __builtin_amdgcn_mfma_f32_16x16x32_bf16(a[tt], B[1][kt], acc[tt][1], 0, 0, 0);
            }
        }
        int crow0 = kgrp * 4;
#pragma unroll
        for (int tt = 0; tt < 4; ++tt) {
            int tile = t0 + tt;
            if (tile < ntile) {
                int r0 = tile * 16;
#pragma unroll
                for (int j = 0; j < 4; ++j) {
                    int row = r0 + crow0 + j;
                    zb[(size_t)row * 128 + col0] = f2b(acc[tt][0][j] + cv0);
                    zb[(size_t)row * 128 + col1] = f2b(acc[tt][1][j] + cv1);
                }
            }
        }
    }
}

// ---------------- CSR-pull aggregate + relu + BN stats (one node per wave) ----------------
// node forced wave-uniform via readfirstlane -> edge stream loads scalarize (s_load),
// gather address = SGPR base + fixed lane offset. 4B edge records, f16 weight.
__global__ __launch_bounds__(256) void k_agg(const unsigned short* __restrict__ zb,
                                             const int* __restrict__ row_ptr,
                                             const unsigned int* __restrict__ ew,
                                             const float* __restrict__ bias,
                                             unsigned int* __restrict__ tb,
                                             float* __restrict__ stats64, int n) {
    int tid = threadIdx.x;
    int l = tid & 63;
    int node = __builtin_amdgcn_readfirstlane(blockIdx.x * 4 + (tid >> 6));
    const unsigned int* zl = (const unsigned int*)zb + l;
    float acc0 = bias[2 * l], acc1 = bias[2 * l + 1];
    int e0 = row_ptr[node], e1 = row_ptr[node + 1];
    unsigned int q[8];
#pragma unroll
    for (int j = 0; j < 8; ++j) q[j] = ew[e0 + j];
    int iters = (e1 - e0) >> 3;
    for (int it = 1; it <= iters; ++it) {
        unsigned int u[8];
        float wf[8];
#pragma unroll
        for (int j = 0; j < 8; ++j) {
            u[j] = zl[(q[j] >> 16) << 6];
            wf[j] = __half2float(__ushort_as_half((unsigned short)(q[j] & 0xffffu)));
        }
        int eb = e0 + it * 8;  // last iteration prefetches slack region (unused)
#pragma unroll
        for (int j = 0; j < 8; ++j) q[j] = ew[eb + j];
#pragma unroll
        for (int j = 0; j < 8; ++j) {
            acc0 = fmaf(wf[j], b2f_lo(u[j]), acc0);
            acc1 = fmaf(wf[j], b2f_hi(u[j]), acc1);
        }
    }
    acc0 = fmaxf(acc0, 0.f);
    acc1 = fmaxf(acc1, 0.f);
    tb[((size_t)node << 6) | l] = pack2(acc0, acc1);
    __shared__ float red[4][256];
    red[0][tid] = acc0; red[1][tid] = acc1;
    red[2][tid] = acc0 * acc0; red[3][tid] = acc1 * acc1;
    __syncthreads();
    int k = tid >> 6, li = tid & 63;
    float v = red[k][li] + red[k][64 + li] + red[k][128 + li] + red[k][192 + li];
    int f = 2 * li + (k & 1) + ((k >> 1) ? 128 : 0);
    atomicAdd(&stats64[(blockIdx.x & 63) * 256 + f], v);
}

// ---------------- fused BN finalize + shift-dots + B pre-scale ----------------
template <int MODE>
__global__ void k_bn_findots(const float* __restrict__ stats64,
                             const float* __restrict__ g, const float* __restrict__ be,
                             float invn, float* __restrict__ ss_out,
                             const float* __restrict__ Wn, float* __restrict__ cn,
                             const float* __restrict__ Wl, const float* __restrict__ base,
                             float* __restrict__ cl,
                             const unsigned short* __restrict__ bpn_src,
                             unsigned short* __restrict__ bpn_dst,
                             const unsigned short* __restrict__ bpl_src,
                             unsigned short* __restrict__ bpl_dst) {
    int tid = threadIdx.x;  // 256
    float a = 0.f;
#pragma unroll 8
    for (int c = 0; c < 64; ++c) a += stats64[c * 256 + tid];
    __shared__ float sums[256];
    __shared__ float sh[128];
    __shared__ float scs[128];
    sums[tid] = a;
    __syncthreads();
    if (tid < 128) {
        float m = sums[tid] * invn;
        float var = sums[128 + tid] * invn - m * m;
        float sc = g[tid] * rsqrtf(var + BN_EPS);
        scs[tid] = sc;
        sh[tid] = fmaf(-m, sc, be[tid]);
    }
    __syncthreads();
    if (blockIdx.x == 0 && tid < 128) {
        ss_out[tid] = scs[tid];
        ss_out[128 + tid] = sh[tid];
    }
    bool doCl = (MODE == 2) ? (blockIdx.x == 0) : (blockIdx.x == 1);
    bool doCn = (MODE < 2) && (blockIdx.x == 0);
    if (doCl || doCn) {
        const float* W = doCl ? Wl : Wn;
        int col = tid & 127, half = tid >> 7;
        float acc = 0.f;
#pragma unroll 4
        for (int k = half * 64; k < half * 64 + 64; ++k) acc = fmaf(sh[k], W[k * 128 + col], acc);
        __syncthreads();
        sums[tid] = acc;
        __syncthreads();
        if (tid < 128) {
            float tot = sums[tid] + sums[128 + tid];
            if (doCl) cl[tid] = ((MODE == 0) ? base[tid] : cl[tid]) + tot;
            else cn[tid] = tot;
        }
    }
    // scale prepacked B fragments by per-k scs
    int beg = blockIdx.x * 8192;
    if (MODE < 2) {
        for (int idx = beg + tid; idx < beg + 8192; idx += 256) {
            int k = ((idx >> 9) & 3) * 32 + ((idx >> 7) & 3) * 8 + (idx & 7);
            bpn_dst[idx] = f2b(us2f(bpn_src[idx]) * scs[k]);
        }
    }
    for (int idx = beg + tid; idx < beg + 8192; idx += 256) {
        int k = ((idx >> 9) & 3) * 32 + ((idx >> 7) & 3) * 8 + (idx & 7);
        bpl_dst[idx] = f2b(us2f(bpl_src[idx]) * scs[k]);
    }
}

// ---------------- final GEMM: out = relu([t1|t2|t3] @ BpL + cl), all-reg B, persistent ----------------
__global__ __launch_bounds__(256) void k_gemm_final(const unsigned short* __restrict__ t1,
                                                    const unsigned short* __restrict__ t2,
                                                    const unsigned short* __restrict__ t3,
                                                    const unsigned short* __restrict__ Bp,
                                                    const float* __restrict__ cl,
                                                    float* __restrict__ out, int n) {
    int tid = threadIdx.x;
    int l = tid & 63, w = tid >> 6;
    const short8* bp8 = (const short8*)Bp;
    short8 B[2][12];
#pragma unroll
    for (int b = 0; b < 3; ++b)
#pragma unroll
        for (int i = 0; i < 2; ++i)
#pragma unroll
            for (int kt = 0; kt < 4; ++kt)
                B[i][b * 4 + kt] = bp8[b * 2048 + ((2 * w + i) * 4 + kt) * 64 + l];
    int kgrp = l >> 4, rit = l & 15, ccol = l & 15;
    int ntile = n >> 4;
    int col0 = 2 * w * 16 + ccol, col1 = col0 + 16;
    float cv0 = cl[col0], cv1 = cl[col1];
    const unsigned short* tbs[3] = {t1, t2, t3};
    for (int t0 = blockIdx.x * 4; t0 < ntile; t0 += gridDim.x * 4) {
        f32x4 acc[4][2];
#pragma unroll
        for (int tt = 0; tt < 4; ++tt) { acc[tt][0] = (f32x4)(0.f); acc[tt][1] = (f32x4)(0.f); }
#pragma unroll
        for (int b = 0; b < 3; ++b) {
            const unsigned short* tp = tbs[b];
#pragma unroll
            for (int kt = 0; kt < 4; ++kt) {
                short8 a[4];
#pragma unroll
                for (int tt = 0; tt < 4; ++tt) {
                    int tile = min(t0 + tt, ntile - 1);
                    a[tt] = *(const short8*)(tp + (size_t)(tile * 16 + rit) * 128 + kgrp * 8 + kt * 32);
                }
#pragma unroll
                for (int tt = 0; tt < 4; ++tt) {
                    acc[tt][0] = __builtin_amdgcn_mfma_f32_16x16x32_bf16(a[tt], B[0][b * 4 + kt], acc[tt][0], 0, 0, 0);
                    acc[tt][1] = __builtin_amdgcn_mfma_f32_16x16x32_bf16(a[tt], B[1][b * 4 + kt], acc[tt][1], 0, 0, 0);
                }
            }
        }
        int crow0 = kgrp * 4;
#pragma unroll
        for (int tt = 0; tt < 4; ++tt) {
            int tile = t0 + tt;
            if (tile < ntile) {
                int r0 = tile * 16;
#pragma unroll
                for (int j = 0; j < 4; ++j) {
                    int row = r0 + crow0 + j;
                    out[(size_t)row * 128 + col0] = fmaxf(acc[tt][0][j] + cv0, 0.f);
                    out[(size_t)row * 128 + col1] = fmaxf(acc[tt][1][j] + cv1, 0.f);
                }
            }
        }
    }
}

extern "C" void kernel_launch(void* const* d_in, const int* in_sizes, int n_in,
                              void* d_out, int out_size, void* d_ws, size_t ws_size,
                              hipStream_t stream) {
    const float* x   = (const float*)d_in[0];
    const int*   ei  = (const int*)d_in[1];
    const float* W1  = (const float*)d_in[3];
    const float* b1  = (const float*)d_in[4];
    const float* g1  = (const float*)d_in[5];
    const float* be1 = (const float*)d_in[6];
    const float* W2  = (const float*)d_in[7];
    const float* b2  = (const float*)d_in[8];
    const float* g2  = (const float*)d_in[9];
    const float* be2 = (const float*)d_in[10];
    const float* W3  = (const float*)d_in[11];
    const float* b3  = (const float*)d_in[12];
    const float* g3  = (const float*)d_in[13];
    const float* be3 = (const float*)d_in[14];
    const float* Wl  = (const float*)d_in[15];
    const float* bl  = (const float*)d_in[16];
    float* out = (float*)d_out;

    const int n = N_NODES;
    const int E = in_sizes[1] / 2;

    char* ws = (char*)d_ws;
    size_t off = 0;
    auto alloc = [&](size_t bytes) -> void* {
        void* p = ws + off;
        off += (bytes + 255) & ~((size_t)255);
        return p;
    };
    // zero-region: cnt + 3 striped stats buffers, contiguous, one memset
    int*            cnt     = (int*)alloc((size_t)n * 4);
    float*          st1     = (float*)alloc(64 * 256 * 4);
    float*          st2     = (float*)alloc(64 * 256 * 4);
    float*          st3     = (float*)alloc(64 * 256 * 4);
    size_t zero_bytes = (size_t)((char*)st3 + 64 * 256 * 4 - (char*)cnt);

    float*          dinv    = (float*)alloc((size_t)n * 4);
    int*            row_ptr = (int*)alloc((size_t)(n + 1) * 4);
    int*            cursor  = (int*)alloc((size_t)n * 4);
    int*            bsum    = (int*)alloc(64 * 4);
    float*          ss1     = (float*)alloc(256 * 4);
    float*          ss2     = (float*)alloc(256 * 4);
    float*          ss3     = (float*)alloc(256 * 4);
    float*          c2      = (float*)alloc(128 * 4);
    float*          c3      = (float*)alloc(128 * 4);
    float*          cl      = (float*)alloc(128 * 4);
    unsigned int*   ew      = (unsigned int*)alloc(((size_t)E + 8 * (size_t)n + 64) * 4);
    unsigned short* bp      = (unsigned short*)alloc(6 * 16384 * 2);   // raw prepack
    unsigned short* bpsN    = (unsigned short*)alloc(16384 * 2);       // scaled next-layer W
    unsigned short* bpsL    = (unsigned short*)alloc(3 * 16384 * 2);   // scaled Wl blocks
    unsigned short* zb      = (unsigned short*)alloc((size_t)n * 128 * 2);
    unsigned int*   tb1     = (unsigned int*)alloc((size_t)n * 64 * 4);
    unsigned int*   tb2     = (unsigned int*)alloc((size_t)n * 64 * 4);
    unsigned int*   tb3     = (unsigned int*)alloc((size_t)n * 64 * 4);

    hipMemsetAsync(cnt, 0, zero_bytes, stream);

    // ---- CSR build (padded rows, 4B edge records) ----
    k_deg_count<<<2048, 256, 0, stream>>>(ei, cnt, E);
    int nchunks = (n + SCAN_CHUNK - 1) / SCAN_CHUNK;
    k_chunk_dinv<<<nchunks, 256, 0, stream>>>(cnt, bsum, dinv, n);
    k_local_scan<<<nchunks, 256, 0, stream>>>(cnt, bsum, row_ptr, cursor, n, nchunks);
    k_fill<<<2048, 256, 0, stream>>>(ei, dinv, cursor, ew, E);
    k_pad<<<(n + 255) / 256, 256, 0, stream>>>(cursor, row_ptr, dinv, ew, n);

    k_prepack<<<6, 256, 0, stream>>>(W1, W2, W3, Wl, bp);

    const unsigned short* t1u = (const unsigned short*)tb1;
    const unsigned short* t2u = (const unsigned short*)tb2;
    const unsigned short* t3u = (const unsigned short*)tb3;
    float invn = 1.0f / n;
    int aggblk = n / 4;     // one node per wave
    int gemmblk = 391;      // persistent: 2 groups of 4 tiles per block

    // ---- layer 1 (reads x fp32 directly; raw W1) ----
    k_gemm_z<0, 1><<<gemmblk, 256, 0, stream>>>(x, bp, nullptr, zb, n);
    k_agg<<<aggblk, 256, 0, stream>>>(zb, row_ptr, ew, b1, tb1, st1, n);
    k_bn_findots<0><<<2, 256, 0, stream>>>(st1, g1, be1, invn, ss1, W2, c2, Wl, bl, cl,
                                           bp + 16384, bpsN, bp + 3 * 16384, bpsL);

    // ---- layer 2 (prescaled W2) ----
    k_gemm_z<1, 0><<<gemmblk, 256, 0, stream>>>(t1u, bpsN, c2, zb, n);
    k_agg<<<aggblk, 256, 0, stream>>>(zb, row_ptr, ew, b2, tb2, st2, n);
    k_bn_findots<1><<<2, 256, 0, stream>>>(st2, g2, be2, invn, ss2, W3, c3, Wl + 16384, nullptr, cl,
                                           bp + 2 * 16384, bpsN, bp + 4 * 16384, bpsL + 16384);

    // ---- layer 3 (prescaled W3) ----
    k_gemm_z<1, 0><<<gemmblk, 256, 0, stream>>>(t2u, bpsN, c3, zb, n);
    k_agg<<<aggblk, 256, 0, stream>>>(zb, row_ptr, ew, b3, tb3, st3, n);
    k_bn_findots<2><<<2, 256, 0, stream>>>(st3, g3, be3, invn, ss3, nullptr, nullptr,
                                           Wl + 2 * 16384, nullptr, cl,
                                           nullptr, nullptr, bp + 5 * 16384, bpsL + 2 * 16384);

    // ---- final fused GEMM over K=384 (prescaled Wl, all-reg B) ----
    k_gemm_final<<<gemmblk, 256, 0, stream>>>(t1u, t2u, t3u, bpsL, cl, out, n);
}

// Round 9
// 342.568 us; speedup vs baseline: 1.0453x; 1.0024x over previous
//
#include <hip/hip_runtime.h>
#include <hip/hip_fp16.h>

#define N_NODES 50000
#define BN_EPS 1e-5f
#define SCAN_CHUNK 2048

typedef __attribute__((ext_vector_type(8))) short short8;
typedef __attribute__((ext_vector_type(4))) float f32x4;

__device__ __forceinline__ unsigned short f2b(float x) {
    unsigned int u = __float_as_uint(x);
    unsigned int r = (u + 0x7fffu + ((u >> 16) & 1u)) >> 16;
    return (unsigned short)r;
}
__device__ __forceinline__ float b2f_lo(unsigned int u) { return __uint_as_float(u << 16); }
__device__ __forceinline__ float b2f_hi(unsigned int u) { return __uint_as_float(u & 0xffff0000u); }
__device__ __forceinline__ unsigned int pack2(float lo, float hi) {
    return (unsigned int)f2b(lo) | ((unsigned int)f2b(hi) << 16);
}
__device__ __forceinline__ float us2f(unsigned short s) {
    return __uint_as_float(((unsigned int)s) << 16);
}
// edge record: src node in high 16 bits, fp16 weight in low 16 bits
__device__ __forceinline__ unsigned int pack_edge(int s, float w) {
    return ((unsigned int)s << 16) | (unsigned int)__half_as_ushort(__float2half(w));
}

// per-block int64 detection: odd 32-bit words of first 256 edge entries all zero <=> int64
__device__ __forceinline__ int detect_is64(const int* __restrict__ e, int tid) {
    __shared__ int snz[4];
    int lane = tid & 63, wv = tid >> 6;
    int v = e[2 * tid + 1];
    unsigned long long b = __ballot(v != 0);
    if (lane == 0) snz[wv] = (b != 0ULL) ? 1 : 0;
    __syncthreads();
    return !(snz[0] | snz[1] | snz[2] | snz[3]);
}

__device__ __forceinline__ int edge_at(const int* e32, const long long* e64, int is64, long long idx) {
    return is64 ? (int)e64[idx] : e32[idx];
}

// ---------------- CSR build ----------------
__global__ void k_deg_count(const int* __restrict__ e, int* __restrict__ cnt, int E) {
    int is64 = detect_is64(e, threadIdx.x);
    const long long* e64 = (const long long*)e;
    int i = blockIdx.x * blockDim.x + threadIdx.x;
    int stride = gridDim.x * blockDim.x;
    for (; i < E; i += stride) {
        int d = edge_at(e, e64, is64, (long long)E + i);
        atomicAdd(&cnt[d], 1);
    }
}

// padded row length: real edges + self loop, rounded up to 8
__device__ __forceinline__ int padlen(int c) { return (c + 8) & ~7; }

// chunk sums of padded lengths + dinv computation (fused)
__global__ void k_chunk_dinv(const int* __restrict__ cnt, int* __restrict__ bsum,
                             float* __restrict__ dinv, int n) {
    __shared__ int sb[256];
    int base = blockIdx.x * SCAN_CHUNK;
    int s = 0;
    for (int j = threadIdx.x; j < SCAN_CHUNK; j += 256) {
        int i = base + j;
        if (i < n) {
            int c = cnt[i];
            s += padlen(c);
            dinv[i] = rsqrtf((float)(c + 1));
        }
    }
    sb[threadIdx.x] = s;
    __syncthreads();
    for (int off = 128; off > 0; off >>= 1) {
        if (threadIdx.x < off) sb[threadIdx.x] += sb[threadIdx.x + off];
        __syncthreads();
    }
    if (threadIdx.x == 0) bsum[blockIdx.x] = sb[0];
}

// local exclusive scan; also writes self-loop + zero-weight pad records (positions
// [row_ptr+cnt, row_ptr+padlen) are known here) -> k_pad kernel eliminated.
__global__ void k_local_scan(const int* __restrict__ cnt, const int* __restrict__ bsum,
                             const float* __restrict__ dinv,
                             int* __restrict__ row_ptr, int* __restrict__ cursor,
                             unsigned int* __restrict__ ew, int n, int nchunks) {
    __shared__ int sb[256];
    __shared__ int base_off;
    int tid = threadIdx.x;
    if (tid == 0) {
        int run = 0;
        for (int b = 0; b < blockIdx.x; ++b) run += bsum[b];
        base_off = run;
        if (blockIdx.x == gridDim.x - 1) {
            int tot = run;
            for (int b = blockIdx.x; b < nchunks; ++b) tot += bsum[b];
            row_ptr[n] = tot;
        }
    }
    int base = blockIdx.x * SCAN_CHUNK + tid * 8;
    int c[8], v[8];
    int ts = 0;
#pragma unroll
    for (int j = 0; j < 8; ++j) {
        int i = base + j;
        c[j] = (i < n) ? cnt[i] : 0;
        v[j] = (i < n) ? padlen(c[j]) : 0;
        ts += v[j];
    }
    sb[tid] = ts;
    __syncthreads();
    for (int off = 1; off < 256; off <<= 1) {
        int t = (tid >= off) ? sb[tid - off] : 0;
        __syncthreads();
        sb[tid] += t;
        __syncthreads();
    }
    int excl = sb[tid] - ts + base_off;
#pragma unroll
    for (int j = 0; j < 8; ++j) {
        int i = base + j;
        if (i < n) {
            row_ptr[i] = excl;
            cursor[i] = excl;
            float di = dinv[i];
            ew[excl + c[j]] = pack_edge(i, di * di);      // self loop
            unsigned int padv = (unsigned int)i << 16;     // f16 zero weight
            for (int p = excl + c[j] + 1; p < excl + v[j]; ++p) ew[p] = padv;
        }
        excl += v[j];
    }
}

// XCD-partitioned scatter: block group (bid&7) owns dst range [grp*6250,(grp+1)*6250).
// All appends for a given ew line then come from ONE XCD's L2 -> lines fill fully and
// write back once (fixes the 64B-per-4B-store write amplification seen in r8).
__global__ void k_fill(const int* __restrict__ e, const float* __restrict__ dinv,
                       int* __restrict__ cursor, unsigned int* __restrict__ ew, int E) {
    int is64 = detect_is64(e, threadIdx.x);
    const long long* e64 = (const long long*)e;
    int grp = blockIdx.x & 7;
    int lo = grp * (N_NODES / 8), hi = lo + (N_NODES / 8);
    int i = (blockIdx.x >> 3) * blockDim.x + threadIdx.x;
    int stride = (gridDim.x >> 3) * blockDim.x;
    for (; i < E; i += stride) {
        int d = edge_at(e, e64, is64, (long long)E + i);
        if (d >= lo && d < hi) {
            int s = edge_at(e, e64, is64, i);
            int pos = atomicAdd(&cursor[d], 1);
            ew[pos] = pack_edge(s, dinv[s] * dinv[d]);
        }
    }
}

// ---------------- W prepack into MFMA B-fragment layout (raw bf16) ----------------
__global__ void k_prepack(const float* __restrict__ W1, const float* __restrict__ W2,
                          const float* __restrict__ W3, const float* __restrict__ Wl,
                          unsigned short* __restrict__ bp) {
    int job = blockIdx.x;
    const float* src;
    int rowoff = 0;
    if (job == 0) src = W1;
    else if (job == 1) src = W2;
    else if (job == 2) src = W3;
    else { src = Wl; rowoff = (job - 3) * 128; }
    unsigned short* dst = bp + job * 16384;
    for (int idx = threadIdx.x; idx < 16384; idx += 256) {
        int j = idx & 7, l = (idx >> 3) & 63, kt = (idx >> 9) & 3, nt = idx >> 11;
        int row = kt * 32 + (l >> 4) * 8 + j;
        int col = nt * 16 + (l & 15);
        dst[idx] = f2b(src[(rowoff + row) * 128 + col]);
    }
}

// ---------------- layer GEMM: zb = A @ Bp(+c), B in regs, persistent blocks ----------------
template <int HAS_C, int A32>
__global__ __launch_bounds__(256) void k_gemm_z(const void* __restrict__ Av,
                                                const unsigned short* __restrict__ Bp,
                                                const float* __restrict__ cvec,
                                                unsigned short* __restrict__ zb, int n) {
    int tid = threadIdx.x;
    int l = tid & 63, w = tid >> 6;
    const short8* bp8 = (const short8*)Bp;
    short8 B[2][4];
#pragma unroll
    for (int i = 0; i < 2; ++i)
#pragma unroll
        for (int kt = 0; kt < 4; ++kt)
            B[i][kt] = bp8[((2 * w + i) * 4 + kt) * 64 + l];
    int kgrp = l >> 4, rit = l & 15, ccol = l & 15;
    int ntile = n >> 4;
    int col0 = 2 * w * 16 + ccol, col1 = col0 + 16;
    float cv0 = HAS_C ? cvec[col0] : 0.f;
    float cv1 = HAS_C ? cvec[col1] : 0.f;
    for (int t0 = blockIdx.x * 4; t0 < ntile; t0 += gridDim.x * 4) {
        f32x4 acc[4][2];
#pragma unroll
        for (int tt = 0; tt < 4; ++tt) { acc[tt][0] = (f32x4)(0.f); acc[tt][1] = (f32x4)(0.f); }
#pragma unroll
        for (int kt = 0; kt < 4; ++kt) {
            short8 a[4];
#pragma unroll
            for (int tt = 0; tt < 4; ++tt) {
                int tile = min(t0 + tt, ntile - 1);
                size_t base = (size_t)(tile * 16 + rit) * 128 + kgrp * 8 + kt * 32;
                if (A32) {
                    const float* a32 = (const float*)Av + base;
                    float4 fa = *(const float4*)a32;
                    float4 fb = *(const float4*)(a32 + 4);
                    short8 af;
                    af[0] = (short)f2b(fa.x); af[1] = (short)f2b(fa.y);
                    af[2] = (short)f2b(fa.z); af[3] = (short)f2b(fa.w);
                    af[4] = (short)f2b(fb.x); af[5] = (short)f2b(fb.y);
                    af[6] = (short)f2b(fb.z); af[7] = (short)f2b(fb.w);
                    a[tt] = af;
                } else {
                    a[tt] = *(const short8*)((const unsigned short*)Av + base);
                }
            }
#pragma unroll
            for (int tt = 0; tt < 4; ++tt) {
                acc[tt][0] = __builtin_amdgcn_mfma_f32_16x16x32_bf16(a[tt], B[0][kt], acc[tt][0], 0, 0, 0);
                acc[tt][1] = __builtin_amdgcn_mfma_f32_16x16x32_bf16(a[tt], B[1][kt], acc[tt][1], 0, 0, 0);
            }
        }
        int crow0 = kgrp * 4;
#pragma unroll
        for (int tt = 0; tt < 4; ++tt) {
            int tile = t0 + tt;
            if (tile < ntile) {
                int r0 = tile * 16;
#pragma unroll
                for (int j = 0; j < 4; ++j) {
                    int row = r0 + crow0 + j;
                    zb[(size_t)row * 128 + col0] = f2b(acc[tt][0][j] + cv0);
                    zb[(size_t)row * 128 + col1] = f2b(acc[tt][1][j] + cv1);
                }
            }
        }
    }
}

// ---------------- CSR-pull aggregate + relu + BN stats (one node per wave) ----------------
__global__ __launch_bounds__(256) void k_agg(const unsigned short* __restrict__ zb,
                                             const int* __restrict__ row_ptr,
                                             const unsigned int* __restrict__ ew,
                                             const float* __restrict__ bias,
                                             unsigned int* __restrict__ tb,
                                             float* __restrict__ stats64, int n) {
    int tid = threadIdx.x;
    int l = tid & 63;
    int node = __builtin_amdgcn_readfirstlane(blockIdx.x * 4 + (tid >> 6));
    const unsigned int* zl = (const unsigned int*)zb + l;
    float acc0 = bias[2 * l], acc1 = bias[2 * l + 1];
    int e0 = row_ptr[node], e1 = row_ptr[node + 1];
    unsigned int q[8];
#pragma unroll
    for (int j = 0; j < 8; ++j) q[j] = ew[e0 + j];
    int iters = (e1 - e0) >> 3;
    for (int it = 1; it <= iters; ++it) {
        unsigned int u[8];
        float wf[8];
#pragma unroll
        for (int j = 0; j < 8; ++j) {
            u[j] = zl[(q[j] >> 16) << 6];
            wf[j] = __half2float(__ushort_as_half((unsigned short)(q[j] & 0xffffu)));
        }
        int eb = e0 + it * 8;  // last iteration prefetches slack region (unused)
#pragma unroll
        for (int j = 0; j < 8; ++j) q[j] = ew[eb + j];
#pragma unroll
        for (int j = 0; j < 8; ++j) {
            acc0 = fmaf(wf[j], b2f_lo(u[j]), acc0);
            acc1 = fmaf(wf[j], b2f_hi(u[j]), acc1);
        }
    }
    acc0 = fmaxf(acc0, 0.f);
    acc1 = fmaxf(acc1, 0.f);
    tb[((size_t)node << 6) | l] = pack2(acc0, acc1);
    __shared__ float red[4][256];
    red[0][tid] = acc0; red[1][tid] = acc1;
    red[2][tid] = acc0 * acc0; red[3][tid] = acc1 * acc1;
    __syncthreads();
    int k = tid >> 6, li = tid & 63;
    float v = red[k][li] + red[k][64 + li] + red[k][128 + li] + red[k][192 + li];
    int f = 2 * li + (k & 1) + ((k >> 1) ? 128 : 0);
    atomicAdd(&stats64[(blockIdx.x & 63) * 256 + f], v);
}

// ---------------- fused BN finalize + shift-dots + B pre-scale ----------------
template <int MODE>
__global__ void k_bn_findots(const float* __restrict__ stats64,
                             const float* __restrict__ g, const float* __restrict__ be,
                             float invn, float* __restrict__ ss_out,
                             const float* __restrict__ Wn, float* __restrict__ cn,
                             const float* __restrict__ Wl, const float* __restrict__ base,
                             float* __restrict__ cl,
                             const unsigned short* __restrict__ bpn_src,
                             unsigned short* __restrict__ bpn_dst,
                             const unsigned short* __restrict__ bpl_src,
                             unsigned short* __restrict__ bpl_dst) {
    int tid = threadIdx.x;  // 256
    float a = 0.f;
#pragma unroll 8
    for (int c = 0; c < 64; ++c) a += stats64[c * 256 + tid];
    __shared__ float sums[256];
    __shared__ float sh[128];
    __shared__ float scs[128];
    sums[tid] = a;
    __syncthreads();
    if (tid < 128) {
        float m = sums[tid] * invn;
        float var = sums[128 + tid] * invn - m * m;
        float sc = g[tid] * rsqrtf(var + BN_EPS);
        scs[tid] = sc;
        sh[tid] = fmaf(-m, sc, be[tid]);
    }
    __syncthreads();
    if (blockIdx.x == 0 && tid < 128) {
        ss_out[tid] = scs[tid];
        ss_out[128 + tid] = sh[tid];
    }
    bool doCl = (MODE == 2) ? (blockIdx.x == 0) : (blockIdx.x == 1);
    bool doCn = (MODE < 2) && (blockIdx.x == 0);
    if (doCl || doCn) {
        const float* W = doCl ? Wl : Wn;
        int col = tid & 127, half = tid >> 7;
        float acc = 0.f;
#pragma unroll 4
        for (int k = half * 64; k < half * 64 + 64; ++k) acc = fmaf(sh[k], W[k * 128 + col], acc);
        __syncthreads();
        sums[tid] = acc;
        __syncthreads();
        if (tid < 128) {
            float tot = sums[tid] + sums[128 + tid];
            if (doCl) cl[tid] = ((MODE == 0) ? base[tid] : cl[tid]) + tot;
            else cn[tid] = tot;
        }
    }
    // scale prepacked B fragments by per-k scs
    int beg = blockIdx.x * 8192;
    if (MODE < 2) {
        for (int idx = beg + tid; idx < beg + 8192; idx += 256) {
            int k = ((idx >> 9) & 3) * 32 + ((idx >> 7) & 3) * 8 + (idx & 7);
            bpn_dst[idx] = f2b(us2f(bpn_src[idx]) * scs[k]);
        }
    }
    for (int idx = beg + tid; idx < beg + 8192; idx += 256) {
        int k = ((idx >> 9) & 3) * 32 + ((idx >> 7) & 3) * 8 + (idx & 7);
        bpl_dst[idx] = f2b(us2f(bpl_src[idx]) * scs[k]);
    }
}

// ---------------- final GEMM: out = relu([t1|t2|t3] @ BpL + cl), all-reg B, persistent ----------------
__global__ __launch_bounds__(256) void k_gemm_final(const unsigned short* __restrict__ t1,
                                                    const unsigned short* __restrict__ t2,
                                                    const unsigned short* __restrict__ t3,
                                                    const unsigned short* __restrict__ Bp,
                                                    const float* __restrict__ cl,
                                                    float* __restrict__ out, int n) {
    int tid = threadIdx.x;
    int l = tid & 63, w = tid >> 6;
    const short8* bp8 = (const short8*)Bp;
    short8 B[2][12];
#pragma unroll
    for (int b = 0; b < 3; ++b)
#pragma unroll
        for (int i = 0; i < 2; ++i)
#pragma unroll
            for (int kt = 0; kt < 4; ++kt)
                B[i][b * 4 + kt] = bp8[b * 2048 + ((2 * w + i) * 4 + kt) * 64 + l];
    int kgrp = l >> 4, rit = l & 15, ccol = l & 15;
    int ntile = n >> 4;
    int col0 = 2 * w * 16 + ccol, col1 = col0 + 16;
    float cv0 = cl[col0], cv1 = cl[col1];
    const unsigned short* tbs[3] = {t1, t2, t3};
    for (int t0 = blockIdx.x * 4; t0 < ntile; t0 += gridDim.x * 4) {
        f32x4 acc[4][2];
#pragma unroll
        for (int tt = 0; tt < 4; ++tt) { acc[tt][0] = (f32x4)(0.f); acc[tt][1] = (f32x4)(0.f); }
#pragma unroll
        for (int b = 0; b < 3; ++b) {
            const unsigned short* tp = tbs[b];
#pragma unroll
            for (int kt = 0; kt < 4; ++kt) {
                short8 a[4];
#pragma unroll
                for (int tt = 0; tt < 4; ++tt) {
                    int tile = min(t0 + tt, ntile - 1);
                    a[tt] = *(const short8*)(tp + (size_t)(tile * 16 + rit) * 128 + kgrp * 8 + kt * 32);
                }
#pragma unroll
                for (int tt = 0; tt < 4; ++tt) {
                    acc[tt][0] = __builtin_amdgcn_mfma_f32_16x16x32_bf16(a[tt], B[0][b * 4 + kt], acc[tt][0], 0, 0, 0);
                    acc[tt][1] = __builtin_amdgcn_mfma_f32_16x16x32_bf16(a[tt], B[1][b * 4 + kt], acc[tt][1], 0, 0, 0);
                }
            }
        }
        int crow0 = kgrp * 4;
#pragma unroll
        for (int tt = 0; tt < 4; ++tt) {
            int tile = t0 + tt;
            if (tile < ntile) {
                int r0 = tile * 16;
#pragma unroll
                for (int j = 0; j < 4; ++j) {
                    int row = r0 + crow0 + j;
                    out[(size_t)row * 128 + col0] = fmaxf(acc[tt][0][j] + cv0, 0.f);
                    out[(size_t)row * 128 + col1] = fmaxf(acc[tt][1][j] + cv1, 0.f);
                }
            }
        }
    }
}

extern "C" void kernel_launch(void* const* d_in, const int* in_sizes, int n_in,
                              void* d_out, int out_size, void* d_ws, size_t ws_size,
                              hipStream_t stream) {
    const float* x   = (const float*)d_in[0];
    const int*   ei  = (const int*)d_in[1];
    const float* W1  = (const float*)d_in[3];
    const float* b1  = (const float*)d_in[4];
    const float* g1  = (const float*)d_in[5];
    const float* be1 = (const float*)d_in[6];
    const float* W2  = (const float*)d_in[7];
    const float* b2  = (const float*)d_in[8];
    const float* g2  = (const float*)d_in[9];
    const float* be2 = (const float*)d_in[10];
    const float* W3  = (const float*)d_in[11];
    const float* b3  = (const float*)d_in[12];
    const float* g3  = (const float*)d_in[13];
    const float* be3 = (const float*)d_in[14];
    const float* Wl  = (const float*)d_in[15];
    const float* bl  = (const float*)d_in[16];
    float* out = (float*)d_out;

    const int n = N_NODES;
    const int E = in_sizes[1] / 2;

    char* ws = (char*)d_ws;
    size_t off = 0;
    auto alloc = [&](size_t bytes) -> void* {
        void* p = ws + off;
        off += (bytes + 255) & ~((size_t)255);
        return p;
    };
    // zero-region: cnt + 3 striped stats buffers, contiguous, one memset
    int*            cnt     = (int*)alloc((size_t)n * 4);
    float*          st1     = (float*)alloc(64 * 256 * 4);
    float*          st2     = (float*)alloc(64 * 256 * 4);
    float*          st3     = (float*)alloc(64 * 256 * 4);
    size_t zero_bytes = (size_t)((char*)st3 + 64 * 256 * 4 - (char*)cnt);

    float*          dinv    = (float*)alloc((size_t)n * 4);
    int*            row_ptr = (int*)alloc((size_t)(n + 1) * 4);
    int*            cursor  = (int*)alloc((size_t)n * 4);
    int*            bsum    = (int*)alloc(64 * 4);
    float*          ss1     = (float*)alloc(256 * 4);
    float*          ss2     = (float*)alloc(256 * 4);
    float*          ss3     = (float*)alloc(256 * 4);
    float*          c2      = (float*)alloc(128 * 4);
    float*          c3      = (float*)alloc(128 * 4);
    float*          cl      = (float*)alloc(128 * 4);
    unsigned int*   ew      = (unsigned int*)alloc(((size_t)E + 8 * (size_t)n + 64) * 4);
    unsigned short* bp      = (unsigned short*)alloc(6 * 16384 * 2);   // raw prepack
    unsigned short* bpsN    = (unsigned short*)alloc(16384 * 2);       // scaled next-layer W
    unsigned short* bpsL    = (unsigned short*)alloc(3 * 16384 * 2);   // scaled Wl blocks
    unsigned short* zb      = (unsigned short*)alloc((size_t)n * 128 * 2);
    unsigned int*   tb1     = (unsigned int*)alloc((size_t)n * 64 * 4);
    unsigned int*   tb2     = (unsigned int*)alloc((size_t)n * 64 * 4);
    unsigned int*   tb3     = (unsigned int*)alloc((size_t)n * 64 * 4);

    hipMemsetAsync(cnt, 0, zero_bytes, stream);

    // ---- CSR build (padded rows, 4B records, XCD-partitioned scatter) ----
    k_deg_count<<<2048, 256, 0, stream>>>(ei, cnt, E);
    int nchunks = (n + SCAN_CHUNK - 1) / SCAN_CHUNK;
    k_chunk_dinv<<<nchunks, 256, 0, stream>>>(cnt, bsum, dinv, n);
    k_local_scan<<<nchunks, 256, 0, stream>>>(cnt, bsum, dinv, row_ptr, cursor, ew, n, nchunks);
    k_fill<<<2048, 256, 0, stream>>>(ei, dinv, cursor, ew, E);

    k_prepack<<<6, 256, 0, stream>>>(W1, W2, W3, Wl, bp);

    const unsigned short* t1u = (const unsigned short*)tb1;
    const unsigned short* t2u = (const unsigned short*)tb2;
    const unsigned short* t3u = (const unsigned short*)tb3;
    float invn = 1.0f / n;
    int aggblk = n / 4;     // one node per wave
    int gemmblk = 391;      // persistent: 2 groups of 4 tiles per block

    // ---- layer 1 (reads x fp32 directly; raw W1) ----
    k_gemm_z<0, 1><<<gemmblk, 256, 0, stream>>>(x, bp, nullptr, zb, n);
    k_agg<<<aggblk, 256, 0, stream>>>(zb, row_ptr, ew, b1, tb1, st1, n);
    k_bn_findots<0><<<2, 256, 0, stream>>>(st1, g1, be1, invn, ss1, W2, c2, Wl, bl, cl,
                                           bp + 16384, bpsN, bp + 3 * 16384, bpsL);

    // ---- layer 2 (prescaled W2) ----
    k_gemm_z<1, 0><<<gemmblk, 256, 0, stream>>>(t1u, bpsN, c2, zb, n);
    k_agg<<<aggblk, 256, 0, stream>>>(zb, row_ptr, ew, b2, tb2, st2, n);
    k_bn_findots<1><<<2, 256, 0, stream>>>(st2, g2, be2, invn, ss2, W3, c3, Wl + 16384, nullptr, cl,
                                           bp + 2 * 16384, bpsN, bp + 4 * 16384, bpsL + 16384);

    // ---- layer 3 (prescaled W3) ----
    k_gemm_z<1, 0><<<gemmblk, 256, 0, stream>>>(t2u, bpsN, c3, zb, n);
    k_agg<<<aggblk, 256, 0, stream>>>(zb, row_ptr, ew, b3, tb3, st3, n);
    k_bn_findots<2><<<2, 256, 0, stream>>>(st3, g3, be3, invn, ss3, nullptr, nullptr,
                                           Wl + 2 * 16384, nullptr, cl,
                                           nullptr, nullptr, bp + 5 * 16384, bpsL + 2 * 16384);

    // ---- final fused GEMM over K=384 (prescaled Wl, all-reg B) ----
    k_gemm_final<<<gemmblk, 256, 0, stream>>>(t1u, t2u, t3u, bpsL, cl, out, n);
}

// Round 10
// 307.051 us; speedup vs baseline: 1.1662x; 1.1157x over previous
//
#include <hip/hip_runtime.h>

#define N_NODES 50000
#define BN_EPS 1e-5f
#define SCAN_CHUNK 2048
#define GEMMBLK 391
#define FILLBLK 2048
#define PREPBLK 24

typedef __attribute__((ext_vector_type(8))) short short8;
typedef __attribute__((ext_vector_type(4))) float f32x4;

__device__ __forceinline__ unsigned short f2b(float x) {
    unsigned int u = __float_as_uint(x);
    unsigned int r = (u + 0x7fffu + ((u >> 16) & 1u)) >> 16;
    return (unsigned short)r;
}
__device__ __forceinline__ float b2f_lo(unsigned int u) { return __uint_as_float(u << 16); }
__device__ __forceinline__ float b2f_hi(unsigned int u) { return __uint_as_float(u & 0xffff0000u); }
__device__ __forceinline__ unsigned int pack2(float lo, float hi) {
    return (unsigned int)f2b(lo) | ((unsigned int)f2b(hi) << 16);
}
__device__ __forceinline__ float us2f(unsigned short s) {
    return __uint_as_float(((unsigned int)s) << 16);
}

// per-block int64 detection: odd 32-bit words of first 256 edge entries all zero <=> int64
__device__ __forceinline__ int detect_is64(const int* __restrict__ e, int tid) {
    __shared__ int snz[4];
    int lane = tid & 63, wv = tid >> 6;
    int v = e[2 * tid + 1];
    unsigned long long b = __ballot(v != 0);
    if (lane == 0) snz[wv] = (b != 0ULL) ? 1 : 0;
    __syncthreads();
    return !(snz[0] | snz[1] | snz[2] | snz[3]);
}

__device__ __forceinline__ int edge_at(const int* e32, const long long* e64, int is64, long long idx) {
    return is64 ? (int)e64[idx] : e32[idx];
}

// padded row length: real edges + self loop, rounded up to 8
__device__ __forceinline__ int padlen(int c) { return (c + 8) & ~7; }

// ---------------- fused deg_count (strided counters) + W prepack ----------------
__global__ void k_deg_prepack(const int* __restrict__ e, int* __restrict__ cnt16,
                              const float* __restrict__ W1, const float* __restrict__ W2,
                              const float* __restrict__ W3, const float* __restrict__ Wl,
                              unsigned short* __restrict__ bp, int E) {
    if (blockIdx.x < PREPBLK) {
        int job = blockIdx.x >> 2, q = blockIdx.x & 3;
        const float* src;
        int rowoff = 0;
        if (job == 0) src = W1;
        else if (job == 1) src = W2;
        else if (job == 2) src = W3;
        else { src = Wl; rowoff = (job - 3) * 128; }
        unsigned short* dst = bp + job * 16384;
        for (int idx = q * 4096 + threadIdx.x; idx < q * 4096 + 4096; idx += 256) {
            int j = idx & 7, l = (idx >> 3) & 63, kt = (idx >> 9) & 3, nt = idx >> 11;
            int row = kt * 32 + (l >> 4) * 8 + j;
            int col = nt * 16 + (l & 15);
            dst[idx] = f2b(src[(rowoff + row) * 128 + col]);
        }
        return;
    }
    int is64 = detect_is64(e, threadIdx.x);
    const long long* e64 = (const long long*)e;
    int i = (blockIdx.x - PREPBLK) * blockDim.x + threadIdx.x;
    int stride = (gridDim.x - PREPBLK) * blockDim.x;
    for (; i < E; i += stride) {
        int d = edge_at(e, e64, is64, (long long)E + i);
        atomicAdd(&cnt16[d << 4], 1);   // one counter per 64B line
    }
}

// chunk sums of padded lengths + dinv computation (fused)
__global__ void k_chunk_dinv(const int* __restrict__ cnt16, int* __restrict__ bsum,
                             float* __restrict__ dinv, int n) {
    __shared__ int sb[256];
    int base = blockIdx.x * SCAN_CHUNK;
    int s = 0;
    for (int j = threadIdx.x; j < SCAN_CHUNK; j += 256) {
        int i = base + j;
        if (i < n) {
            int c = cnt16[i << 4];
            s += padlen(c);
            dinv[i] = rsqrtf((float)(c + 1));
        }
    }
    sb[threadIdx.x] = s;
    __syncthreads();
    for (int off = 128; off > 0; off >>= 1) {
        if (threadIdx.x < off) sb[threadIdx.x] += sb[threadIdx.x + off];
        __syncthreads();
    }
    if (threadIdx.x == 0) bsum[blockIdx.x] = sb[0];
}

// local exclusive scan; writes strided cursor + self-loop/pad u16 records.
// ZROW = N_NODES points at a zeroed zb row -> pads contribute exactly 0.
__global__ void k_local_scan(const int* __restrict__ cnt16, const int* __restrict__ bsum,
                             int* __restrict__ row_ptr, int* __restrict__ cursor16,
                             unsigned short* __restrict__ ew, int n, int nchunks) {
    __shared__ int sb[256];
    __shared__ int base_off;
    int tid = threadIdx.x;
    if (tid == 0) {
        int run = 0;
        for (int b = 0; b < blockIdx.x; ++b) run += bsum[b];
        base_off = run;
        if (blockIdx.x == gridDim.x - 1) {
            int tot = run;
            for (int b = blockIdx.x; b < nchunks; ++b) tot += bsum[b];
            row_ptr[n] = tot;
        }
    }
    int base = blockIdx.x * SCAN_CHUNK + tid * 8;
    int c[8], v[8];
    int ts = 0;
#pragma unroll
    for (int j = 0; j < 8; ++j) {
        int i = base + j;
        c[j] = (i < n) ? cnt16[i << 4] : 0;
        v[j] = (i < n) ? padlen(c[j]) : 0;
        ts += v[j];
    }
    sb[tid] = ts;
    __syncthreads();
    for (int off = 1; off < 256; off <<= 1) {
        int t = (tid >= off) ? sb[tid - off] : 0;
        __syncthreads();
        sb[tid] += t;
        __syncthreads();
    }
    int excl = sb[tid] - ts + base_off;
#pragma unroll
    for (int j = 0; j < 8; ++j) {
        int i = base + j;
        if (i < n) {
            row_ptr[i] = excl;
            cursor16[i << 4] = excl;
            ew[excl + c[j]] = (unsigned short)i;            // self loop
            for (int p = excl + c[j] + 1; p < excl + v[j]; ++p)
                ew[p] = (unsigned short)N_NODES;            // pad -> zero row
        }
        excl += v[j];
    }
}

// ---------------- shared GEMM body: zb = dinv .* (A @ Bp + c), bf16 out ----------------
template <int HAS_C, int A32>
__device__ __forceinline__ void gemm_body(int bid, int nblocks, const void* __restrict__ Av,
                                          const unsigned short* __restrict__ Bp,
                                          const float* __restrict__ cvec,
                                          const float* __restrict__ dinv,
                                          unsigned short* __restrict__ zb, int n) {
    int tid = threadIdx.x;
    int l = tid & 63, w = tid >> 6;
    const short8* bp8 = (const short8*)Bp;
    short8 B[2][4];
#pragma unroll
    for (int i = 0; i < 2; ++i)
#pragma unroll
        for (int kt = 0; kt < 4; ++kt)
            B[i][kt] = bp8[((2 * w + i) * 4 + kt) * 64 + l];
    int kgrp = l >> 4, rit = l & 15, ccol = l & 15;
    int ntile = n >> 4;
    int col0 = 2 * w * 16 + ccol, col1 = col0 + 16;
    float cv0 = HAS_C ? cvec[col0] : 0.f;
    float cv1 = HAS_C ? cvec[col1] : 0.f;
    for (int t0 = bid * 4; t0 < ntile; t0 += nblocks * 4) {
        f32x4 acc[4][2];
#pragma unroll
        for (int tt = 0; tt < 4; ++tt) { acc[tt][0] = (f32x4)(0.f); acc[tt][1] = (f32x4)(0.f); }
#pragma unroll
        for (int kt = 0; kt < 4; ++kt) {
            short8 a[4];
#pragma unroll
            for (int tt = 0; tt < 4; ++tt) {
                int tile = min(t0 + tt, ntile - 1);
                size_t base = (size_t)(tile * 16 + rit) * 128 + kgrp * 8 + kt * 32;
                if (A32) {
                    const float* a32 = (const float*)Av + base;
                    float4 fa = *(const float4*)a32;
                    float4 fb = *(const float4*)(a32 + 4);
                    short8 af;
                    af[0] = (short)f2b(fa.x); af[1] = (short)f2b(fa.y);
                    af[2] = (short)f2b(fa.z); af[3] = (short)f2b(fa.w);
                    af[4] = (short)f2b(fb.x); af[5] = (short)f2b(fb.y);
                    af[6] = (short)f2b(fb.z); af[7] = (short)f2b(fb.w);
                    a[tt] = af;
                } else {
                    a[tt] = *(const short8*)((const unsigned short*)Av + base);
                }
            }
#pragma unroll
            for (int tt = 0; tt < 4; ++tt) {
                acc[tt][0] = __builtin_amdgcn_mfma_f32_16x16x32_bf16(a[tt], B[0][kt], acc[tt][0], 0, 0, 0);
                acc[tt][1] = __builtin_amdgcn_mfma_f32_16x16x32_bf16(a[tt], B[1][kt], acc[tt][1], 0, 0, 0);
            }
        }
        int crow0 = kgrp * 4;
#pragma unroll
        for (int tt = 0; tt < 4; ++tt) {
            int tile = t0 + tt;
            if (tile < ntile) {
                int r0 = tile * 16;
#pragma unroll
                for (int j = 0; j < 4; ++j) {
                    int row = r0 + crow0 + j;
                    float dv = dinv[row];
                    zb[(size_t)row * 128 + col0] = f2b((acc[tt][0][j] + cv0) * dv);
                    zb[(size_t)row * 128 + col1] = f2b((acc[tt][1][j] + cv1) * dv);
                }
            }
        }
    }
}

// ---------------- fill body: scatter u16 src records (strided cursor) ----------------
__device__ __forceinline__ void fill_body(int bid, int nblocks, const int* __restrict__ e,
                                          int* __restrict__ cursor16,
                                          unsigned short* __restrict__ ew, int E) {
    int is64 = detect_is64(e, threadIdx.x);
    const long long* e64 = (const long long*)e;
    int i = bid * 256 + threadIdx.x;
    int stride = nblocks * 256;
    for (; i < E; i += stride) {
        int d = edge_at(e, e64, is64, (long long)E + i);
        int s = edge_at(e, e64, is64, i);
        int pos = atomicAdd(&cursor16[d << 4], 1);
        ew[pos] = (unsigned short)s;
    }
}

// fused layer-1 GEMM + edge fill (independent work; fill latency hides under MFMA)
__global__ __launch_bounds__(256) void k_gemm1_fill(const float* __restrict__ x,
                                                    const unsigned short* __restrict__ Bp,
                                                    const float* __restrict__ dinv,
                                                    unsigned short* __restrict__ zb,
                                                    const int* __restrict__ e,
                                                    int* __restrict__ cursor16,
                                                    unsigned short* __restrict__ ew,
                                                    int E, int n) {
    if (blockIdx.x < GEMMBLK)
        gemm_body<0, 1>(blockIdx.x, GEMMBLK, x, Bp, nullptr, dinv, zb, n);
    else
        fill_body(blockIdx.x - GEMMBLK, FILLBLK, e, cursor16, ew, E);
}

// standalone layer GEMM (layers 2,3)
template <int HAS_C, int A32>
__global__ __launch_bounds__(256) void k_gemm_z(const void* __restrict__ Av,
                                                const unsigned short* __restrict__ Bp,
                                                const float* __restrict__ cvec,
                                                const float* __restrict__ dinv,
                                                unsigned short* __restrict__ zb, int n) {
    gemm_body<HAS_C, A32>(blockIdx.x, gridDim.x, Av, Bp, cvec, dinv, zb, n);
}

// ---------------- CSR-pull aggregate + relu + BN stats (one node per wave) ----------------
// Weightless edges: acc = dinv[node] * sum(zb'[src]) + bias; pads hit zero row.
__global__ __launch_bounds__(256) void k_agg(const unsigned short* __restrict__ zb,
                                             const int* __restrict__ row_ptr,
                                             const unsigned short* __restrict__ ew,
                                             const float* __restrict__ dinv,
                                             const float* __restrict__ bias,
                                             unsigned int* __restrict__ tb,
                                             float* __restrict__ stats64, int n) {
    int tid = threadIdx.x;
    int l = tid & 63;
    int node = __builtin_amdgcn_readfirstlane(blockIdx.x * 4 + (tid >> 6));
    const unsigned int* zl = (const unsigned int*)zb + l;
    float s0 = 0.f, s1 = 0.f;
    int e0 = row_ptr[node], e1 = row_ptr[node + 1];
    const uint4* ep = (const uint4*)(ew + e0);   // e0 multiple of 8 -> 16B aligned
    int nIter = (e1 - e0) >> 3;
    uint4 q = ep[0];
    for (int it = 1; it <= nIter; ++it) {
        unsigned int u0 = zl[(q.x & 0xffffu) << 6];
        unsigned int u1 = zl[(q.x >> 16) << 6];
        unsigned int u2 = zl[(q.y & 0xffffu) << 6];
        unsigned int u3 = zl[(q.y >> 16) << 6];
        unsigned int u4 = zl[(q.z & 0xffffu) << 6];
        unsigned int u5 = zl[(q.z >> 16) << 6];
        unsigned int u6 = zl[(q.w & 0xffffu) << 6];
        unsigned int u7 = zl[(q.w >> 16) << 6];
        q = ep[it];  // prefetch next 8 (slack-safe past end)
        s0 += b2f_lo(u0); s1 += b2f_hi(u0);
        s0 += b2f_lo(u1); s1 += b2f_hi(u1);
        s0 += b2f_lo(u2); s1 += b2f_hi(u2);
        s0 += b2f_lo(u3); s1 += b2f_hi(u3);
        s0 += b2f_lo(u4); s1 += b2f_hi(u4);
        s0 += b2f_lo(u5); s1 += b2f_hi(u5);
        s0 += b2f_lo(u6); s1 += b2f_hi(u6);
        s0 += b2f_lo(u7); s1 += b2f_hi(u7);
    }
    float dd = dinv[node];
    float acc0 = fmaxf(fmaf(s0, dd, bias[2 * l]), 0.f);
    float acc1 = fmaxf(fmaf(s1, dd, bias[2 * l + 1]), 0.f);
    tb[((size_t)node << 6) | l] = pack2(acc0, acc1);
    __shared__ float red[4][256];
    red[0][tid] = acc0; red[1][tid] = acc1;
    red[2][tid] = acc0 * acc0; red[3][tid] = acc1 * acc1;
    __syncthreads();
    int k = tid >> 6, li = tid & 63;
    float v = red[k][li] + red[k][64 + li] + red[k][128 + li] + red[k][192 + li];
    int f = 2 * li + (k & 1) + ((k >> 1) ? 128 : 0);
    atomicAdd(&stats64[(blockIdx.x & 63) * 256 + f], v);
}

// ---------------- fused BN finalize + shift-dots + B pre-scale ----------------
template <int MODE>
__global__ void k_bn_findots(const float* __restrict__ stats64,
                             const float* __restrict__ g, const float* __restrict__ be,
                             float invn, float* __restrict__ ss_out,
                             const float* __restrict__ Wn, float* __restrict__ cn,
                             const float* __restrict__ Wl, const float* __restrict__ base,
                             float* __restrict__ cl,
                             const unsigned short* __restrict__ bpn_src,
                             unsigned short* __restrict__ bpn_dst,
                             const unsigned short* __restrict__ bpl_src,
                             unsigned short* __restrict__ bpl_dst) {
    int tid = threadIdx.x;  // 256
    float a = 0.f;
#pragma unroll 8
    for (int c = 0; c < 64; ++c) a += stats64[c * 256 + tid];
    __shared__ float sums[256];
    __shared__ float sh[128];
    __shared__ float scs[128];
    sums[tid] = a;
    __syncthreads();
    if (tid < 128) {
        float m = sums[tid] * invn;
        float var = sums[128 + tid] * invn - m * m;
        float sc = g[tid] * rsqrtf(var + BN_EPS);
        scs[tid] = sc;
        sh[tid] = fmaf(-m, sc, be[tid]);
    }
    __syncthreads();
    if (blockIdx.x == 0 && tid < 128) {
        ss_out[tid] = scs[tid];
        ss_out[128 + tid] = sh[tid];
    }
    bool doCl = (MODE == 2) ? (blockIdx.x == 0) : (blockIdx.x == 1);
    bool doCn = (MODE < 2) && (blockIdx.x == 0);
    if (doCl || doCn) {
        const float* W = doCl ? Wl : Wn;
        int col = tid & 127, half = tid >> 7;
        float acc = 0.f;
#pragma unroll 4
        for (int k = half * 64; k < half * 64 + 64; ++k) acc = fmaf(sh[k], W[k * 128 + col], acc);
        __syncthreads();
        sums[tid] = acc;
        __syncthreads();
        if (tid < 128) {
            float tot = sums[tid] + sums[128 + tid];
            if (doCl) cl[tid] = ((MODE == 0) ? base[tid] : cl[tid]) + tot;
            else cn[tid] = tot;
        }
    }
    // scale prepacked B fragments by per-k scs
    int beg = blockIdx.x * 8192;
    if (MODE < 2) {
        for (int idx = beg + tid; idx < beg + 8192; idx += 256) {
            int k = ((idx >> 9) & 3) * 32 + ((idx >> 7) & 3) * 8 + (idx & 7);
            bpn_dst[idx] = f2b(us2f(bpn_src[idx]) * scs[k]);
        }
    }
    for (int idx = beg + tid; idx < beg + 8192; idx += 256) {
        int k = ((idx >> 9) & 3) * 32 + ((idx >> 7) & 3) * 8 + (idx & 7);
        bpl_dst[idx] = f2b(us2f(bpl_src[idx]) * scs[k]);
    }
}

// ---------------- final GEMM: out = relu([t1|t2|t3] @ BpL + cl), all-reg B, persistent ----------------
__global__ __launch_bounds__(256) void k_gemm_final(const unsigned short* __restrict__ t1,
                                                    const unsigned short* __restrict__ t2,
                                                    const unsigned short* __restrict__ t3,
                                                    const unsigned short* __restrict__ Bp,
                                                    const float* __restrict__ cl,
                                                    float* __restrict__ out, int n) {
    int tid = threadIdx.x;
    int l = tid & 63, w = tid >> 6;
    const short8* bp8 = (const short8*)Bp;
    short8 B[2][12];
#pragma unroll
    for (int b = 0; b < 3; ++b)
#pragma unroll
        for (int i = 0; i < 2; ++i)
#pragma unroll
            for (int kt = 0; kt < 4; ++kt)
                B[i][b * 4 + kt] = bp8[b * 2048 + ((2 * w + i) * 4 + kt) * 64 + l];
    int kgrp = l >> 4, rit = l & 15, ccol = l & 15;
    int ntile = n >> 4;
    int col0 = 2 * w * 16 + ccol, col1 = col0 + 16;
    float cv0 = cl[col0], cv1 = cl[col1];
    const unsigned short* tbs[3] = {t1, t2, t3};
    for (int t0 = blockIdx.x * 4; t0 < ntile; t0 += gridDim.x * 4) {
        f32x4 acc[4][2];
#pragma unroll
        for (int tt = 0; tt < 4; ++tt) { acc[tt][0] = (f32x4)(0.f); acc[tt][1] = (f32x4)(0.f); }
#pragma unroll
        for (int b = 0; b < 3; ++b) {
            const unsigned short* tp = tbs[b];
#pragma unroll
            for (int kt = 0; kt < 4; ++kt) {
                short8 a[4];
#pragma unroll
                for (int tt = 0; tt < 4; ++tt) {
                    int tile = min(t0 + tt, ntile - 1);
                    a[tt] = *(const short8*)(tp + (size_t)(tile * 16 + rit) * 128 + kgrp * 8 + kt * 32);
                }
#pragma unroll
                for (int tt = 0; tt < 4; ++tt) {
                    acc[tt][0] = __builtin_amdgcn_mfma_f32_16x16x32_bf16(a[tt], B[0][b * 4 + kt], acc[tt][0], 0, 0, 0);
                    acc[tt][1] = __builtin_amdgcn_mfma_f32_16x16x32_bf16(a[tt], B[1][b * 4 + kt], acc[tt][1], 0, 0, 0);
                }
            }
        }
        int crow0 = kgrp * 4;
#pragma unroll
        for (int tt = 0; tt < 4; ++tt) {
            int tile = t0 + tt;
            if (tile < ntile) {
                int r0 = tile * 16;
#pragma unroll
                for (int j = 0; j < 4; ++j) {
                    int row = r0 + crow0 + j;
                    out[(size_t)row * 128 + col0] = fmaxf(acc[tt][0][j] + cv0, 0.f);
                    out[(size_t)row * 128 + col1] = fmaxf(acc[tt][1][j] + cv1, 0.f);
                }
            }
        }
    }
}

extern "C" void kernel_launch(void* const* d_in, const int* in_sizes, int n_in,
                              void* d_out, int out_size, void* d_ws, size_t ws_size,
                              hipStream_t stream) {
    const float* x   = (const float*)d_in[0];
    const int*   ei  = (const int*)d_in[1];
    const float* W1  = (const float*)d_in[3];
    const float* b1  = (const float*)d_in[4];
    const float* g1  = (const float*)d_in[5];
    const float* be1 = (const float*)d_in[6];
    const float* W2  = (const float*)d_in[7];
    const float* b2  = (const float*)d_in[8];
    const float* g2  = (const float*)d_in[9];
    const float* be2 = (const float*)d_in[10];
    const float* W3  = (const float*)d_in[11];
    const float* b3  = (const float*)d_in[12];
    const float* g3  = (const float*)d_in[13];
    const float* be3 = (const float*)d_in[14];
    const float* Wl  = (const float*)d_in[15];
    const float* bl  = (const float*)d_in[16];
    float* out = (float*)d_out;

    const int n = N_NODES;
    const int E = in_sizes[1] / 2;

    char* ws = (char*)d_ws;
    size_t off = 0;
    auto alloc = [&](size_t bytes) -> void* {
        void* p = ws + off;
        off += (bytes + 255) & ~((size_t)255);
        return p;
    };
    // zero-region: strided cnt + 3 striped stats buffers, contiguous, one memset
    int*            cnt16    = (int*)alloc((size_t)n * 16 * 4);
    float*          st1      = (float*)alloc(64 * 256 * 4);
    float*          st2      = (float*)alloc(64 * 256 * 4);
    float*          st3      = (float*)alloc(64 * 256 * 4);
    size_t zero_bytes = (size_t)((char*)st3 + 64 * 256 * 4 - (char*)cnt16);

    int*            cursor16 = (int*)alloc((size_t)n * 16 * 4);
    float*          dinv     = (float*)alloc((size_t)n * 4);
    int*            row_ptr  = (int*)alloc((size_t)(n + 1) * 4);
    int*            bsum     = (int*)alloc(64 * 4);
    float*          ss1      = (float*)alloc(256 * 4);
    float*          ss2      = (float*)alloc(256 * 4);
    float*          ss3      = (float*)alloc(256 * 4);
    float*          c2       = (float*)alloc(128 * 4);
    float*          c3       = (float*)alloc(128 * 4);
    float*          cl       = (float*)alloc(128 * 4);
    unsigned short* ew       = (unsigned short*)alloc(((size_t)E + 8 * (size_t)n + 64) * 2);
    unsigned short* bp       = (unsigned short*)alloc(6 * 16384 * 2);   // raw prepack
    unsigned short* bpsN     = (unsigned short*)alloc(16384 * 2);       // scaled next-layer W
    unsigned short* bpsL     = (unsigned short*)alloc(3 * 16384 * 2);   // scaled Wl blocks
    unsigned short* zb       = (unsigned short*)alloc((size_t)(n + 1) * 128 * 2);  // +zero row
    unsigned int*   tb1      = (unsigned int*)alloc((size_t)n * 64 * 4);
    unsigned int*   tb2      = (unsigned int*)alloc((size_t)n * 64 * 4);
    unsigned int*   tb3      = (unsigned int*)alloc((size_t)n * 64 * 4);

    hipMemsetAsync(cnt16, 0, zero_bytes, stream);
    hipMemsetAsync(zb + (size_t)n * 128, 0, 256, stream);   // ZROW for pad edges

    // ---- CSR build ----
    k_deg_prepack<<<FILLBLK + PREPBLK, 256, 0, stream>>>(ei, cnt16, W1, W2, W3, Wl, bp, E);
    int nchunks = (n + SCAN_CHUNK - 1) / SCAN_CHUNK;
    k_chunk_dinv<<<nchunks, 256, 0, stream>>>(cnt16, bsum, dinv, n);
    k_local_scan<<<nchunks, 256, 0, stream>>>(cnt16, bsum, row_ptr, cursor16, ew, n, nchunks);

    const unsigned short* t1u = (const unsigned short*)tb1;
    const unsigned short* t2u = (const unsigned short*)tb2;
    const unsigned short* t3u = (const unsigned short*)tb3;
    float invn = 1.0f / n;
    int aggblk = n / 4;     // one node per wave

    // ---- layer 1 GEMM fused with edge fill ----
    k_gemm1_fill<<<GEMMBLK + FILLBLK, 256, 0, stream>>>(x, bp, dinv, zb, ei, cursor16, ew, E, n);
    k_agg<<<aggblk, 256, 0, stream>>>(zb, row_ptr, ew, dinv, b1, tb1, st1, n);
    k_bn_findots<0><<<2, 256, 0, stream>>>(st1, g1, be1, invn, ss1, W2, c2, Wl, bl, cl,
                                           bp + 16384, bpsN, bp + 3 * 16384, bpsL);

    // ---- layer 2 (prescaled W2) ----
    k_gemm_z<1, 0><<<GEMMBLK, 256, 0, stream>>>(t1u, bpsN, c2, dinv, zb, n);
    k_agg<<<aggblk, 256, 0, stream>>>(zb, row_ptr, ew, dinv, b2, tb2, st2, n);
    k_bn_findots<1><<<2, 256, 0, stream>>>(st2, g2, be2, invn, ss2, W3, c3, Wl + 16384, nullptr, cl,
                                           bp + 2 * 16384, bpsN, bp + 4 * 16384, bpsL + 16384);

    // ---- layer 3 (prescaled W3) ----
    k_gemm_z<1, 0><<<GEMMBLK, 256, 0, stream>>>(t2u, bpsN, c3, dinv, zb, n);
    k_agg<<<aggblk, 256, 0, stream>>>(zb, row_ptr, ew, dinv, b3, tb3, st3, n);
    k_bn_findots<2><<<2, 256, 0, stream>>>(st3, g3, be3, invn, ss3, nullptr, nullptr,
                                           Wl + 2 * 16384, nullptr, cl,
                                           nullptr, nullptr, bp + 5 * 16384, bpsL + 2 * 16384);

    // ---- final fused GEMM over K=384 (prescaled Wl, all-reg B) ----
    k_gemm_final<<<GEMMBLK, 256, 0, stream>>>(t1u, t2u, t3u, bpsL, cl, out, n);
}